// Round 1
// baseline (2204.007 us; speedup 1.0000x reference)
//
#include <hip/hip_runtime.h>
#include <hip/hip_bf16.h>
#include <math.h>

#define THREADS 256

// ---------------- problem constants ----------------
constexpr int B_    = 8;
constexpr int C_    = 768;
constexpr int KS_   = 7;
constexpr int F_IN  = 81;
constexpr int F_SO3 = 300;
constexpr int S2_DIM  = 81;
constexpr int SO3_DIM = 969;
constexpr int G_S2  = 48;
constexpr int G_ACT = 4096;
constexpr int G_SO3 = 36864;
constexpr int CKK   = C_ * KS_ * KS_;   // 37632
constexpr int CKK4  = CKK / 4;          // 9408
constexpr int NPAIR = F_IN * S2_DIM;    // 6561

__constant__ int d_S2_OFF[10]  = {0, 1, 4, 9, 16, 25, 36, 49, 64, 81};
__constant__ int d_SO3_OFF[10] = {0, 1, 10, 35, 84, 165, 286, 455, 680, 969};

// ---------------- workspace layout (floats) ----------------
constexpr size_t WS_Y    = 0;                       // 8*6561        = 52488
constexpr size_t WS_PSI  = 52488;                   // 81*300*81     = 1968300
constexpr size_t WS_Z    = 2020788;                 // 8*300*969     = 2325600
constexpr size_t WS_S    = 4346388;                 // 2400*4096     = 9830400
constexpr size_t WS_Z2   = 14176788;                // 2325600
constexpr size_t WS_P2P  = 16502388;                // 8*300*969     = 2325600
constexpr size_t WS_PSI2 = 18827988;                // 300*969       = 290700
// total: 19118688 floats = 76.5 MB

// ---------------- stage A: y[b, f, s] = dot(F[f,s,:], x[b,:]) ----------------
// F flat = [6561][37632] contiguous; x flat = [8][37632].
__global__ __launch_bounds__(THREADS) void k_stage_a(
    const float* __restrict__ Fm, const float* __restrict__ x, float* __restrict__ y) {
  const int p0  = blockIdx.x * 9;
  const int tid = threadIdx.x;
  const float4* __restrict__ F4 = (const float4*)Fm;
  const float4* __restrict__ x4 = (const float4*)x;

  float acc[9][8];
#pragma unroll
  for (int p = 0; p < 9; ++p)
#pragma unroll
    for (int b = 0; b < 8; ++b) acc[p][b] = 0.f;

  for (int i = tid; i < CKK4; i += THREADS) {
    float4 xv[8];
#pragma unroll
    for (int b = 0; b < 8; ++b) xv[b] = x4[b * CKK4 + i];
#pragma unroll
    for (int p = 0; p < 9; ++p) {
      float4 fv = F4[(size_t)(p0 + p) * CKK4 + i];
#pragma unroll
      for (int b = 0; b < 8; ++b)
        acc[p][b] += fv.x * xv[b].x + fv.y * xv[b].y + fv.z * xv[b].z + fv.w * xv[b].w;
    }
  }

  __shared__ float red[4][72];
  const int lane = tid & 63, wid = tid >> 6;
#pragma unroll
  for (int p = 0; p < 9; ++p) {
#pragma unroll
    for (int b = 0; b < 8; ++b) {
      float v = acc[p][b];
      v += __shfl_down(v, 32);
      v += __shfl_down(v, 16);
      v += __shfl_down(v, 8);
      v += __shfl_down(v, 4);
      v += __shfl_down(v, 2);
      v += __shfl_down(v, 1);
      if (lane == 0) red[wid][p * 8 + b] = v;
    }
  }
  __syncthreads();
  if (tid < 72) {
    float v = red[0][tid] + red[1][tid] + red[2][tid] + red[3][tid];
    int p = tid / 8, b = tid % 8;
    y[(size_t)b * NPAIR + p0 + p] = v;
  }
}

// ---------------- stage B: psi[f,g,s] = sum_n w_s2[f,g,n] * Y[n,s] / sqrt(48) ----------------
__global__ __launch_bounds__(THREADS) void k_psi(
    const float* __restrict__ w_s2, const float* __restrict__ Y, float* __restrict__ psi) {
  int idx = blockIdx.x * THREADS + threadIdx.x;
  if (idx >= F_IN * F_SO3 * S2_DIM) return;
  int s  = idx % S2_DIM;
  int fg = idx / S2_DIM;
  const float* w = w_s2 + (size_t)fg * G_S2;
  float acc = 0.f;
#pragma unroll 8
  for (int n = 0; n < G_S2; ++n) acc += w[n] * Y[n * S2_DIM + s];
  psi[idx] = acc * 0.14433756729740643f;  // 1/sqrt(48)
}

// ---------------- stage C: z[b,g, SO3_OFF[l]+u*d+m] = sum_f y[b,f,so+m]*psi[f,g,so+u] / 9 ----------------
__global__ __launch_bounds__(THREADS) void k_stage_c(
    const float* __restrict__ y, const float* __restrict__ psi, float* __restrict__ z) {
  const int b = blockIdx.x / F_SO3;
  const int g = blockIdx.x % F_SO3;
  __shared__ float ybl[NPAIR];
  __shared__ float psl[NPAIR];
  const int tid = threadIdx.x;
  for (int t = tid; t < NPAIR; t += THREADS) {
    ybl[t] = y[(size_t)b * NPAIR + t];
    int f = t / S2_DIM, s = t % S2_DIM;
    psl[t] = psi[((size_t)f * F_SO3 + g) * S2_DIM + s];
  }
  __syncthreads();
  for (int i = tid; i < SO3_DIM; i += THREADS) {
    int l = 0;
    while (i >= d_SO3_OFF[l + 1]) ++l;
    int d  = 2 * l + 1;
    int r  = i - d_SO3_OFF[l];
    int u  = r / d, m = r - u * d;
    int so = d_S2_OFF[l];
    float acc = 0.f;
#pragma unroll 9
    for (int f = 0; f < F_IN; ++f)
      acc += ybl[f * S2_DIM + so + m] * psl[f * S2_DIM + so + u];
    z[((size_t)b * F_SO3 + g) * SO3_DIM + i] = acc * (1.0f / 9.0f);
  }
}

// ---------------- fp32 tiled GEMM, C = relu(A * B^T) ----------------
// A: MxK (rows K-contig), B: NxK (rows K-contig), C: MxN
__global__ __launch_bounds__(THREADS) void k_gemm_nt_relu(
    const float* __restrict__ A, const float* __restrict__ Bm, float* __restrict__ Cm,
    int M, int N, int K) {
  __shared__ float As[16][68];
  __shared__ float Bs[16][68];
  const int bm = blockIdx.y * 64, bn = blockIdx.x * 64;
  const int t  = threadIdx.x;
  const int lk = t & 15, lm = t >> 4;  // loads
  const int tn = t & 15, tm = t >> 4;  // compute
  float acc[4][4] = {};
  for (int k0 = 0; k0 < K; k0 += 16) {
    int gk = k0 + lk;
#pragma unroll
    for (int j = 0; j < 4; ++j) {
      int m  = lm + 16 * j;
      int gm = bm + m;
      As[lk][m] = (gm < M && gk < K) ? A[(size_t)gm * K + gk] : 0.f;
      int gn = bn + m;
      Bs[lk][m] = (gn < N && gk < K) ? Bm[(size_t)gn * K + gk] : 0.f;
    }
    __syncthreads();
#pragma unroll
    for (int k = 0; k < 16; ++k) {
      float4 av = *(const float4*)&As[k][tm * 4];
      float4 bv = *(const float4*)&Bs[k][tn * 4];
      float a[4] = {av.x, av.y, av.z, av.w};
      float bb[4] = {bv.x, bv.y, bv.z, bv.w};
#pragma unroll
      for (int i2 = 0; i2 < 4; ++i2)
#pragma unroll
        for (int j2 = 0; j2 < 4; ++j2)
          acc[i2][j2] += a[i2] * bb[j2];
    }
    __syncthreads();
  }
#pragma unroll
  for (int i2 = 0; i2 < 4; ++i2) {
    int gm = bm + tm * 4 + i2;
    if (gm >= M) continue;
#pragma unroll
    for (int j2 = 0; j2 < 4; ++j2) {
      int gn = bn + tn * 4 + j2;
      if (gn < N) Cm[(size_t)gm * N + gn] = fmaxf(acc[i2][j2], 0.f);
    }
  }
}

// ---------------- fp32 tiled GEMM, C = scale * (A * B), with K-split via blockIdx.z ----------------
// A: MxK (rows K-contig), B: KxN (rows N-contig), C: MxN (per-split buffer cStride apart)
__global__ __launch_bounds__(THREADS) void k_gemm_nn(
    const float* __restrict__ A, const float* __restrict__ Bm, float* __restrict__ Cm,
    int M, int N, int K, int kSpan, float scale, size_t cStride) {
  __shared__ float As[16][68];
  __shared__ float Bs[16][68];
  const int bm = blockIdx.y * 64, bn = blockIdx.x * 64;
  const int t   = threadIdx.x;
  const int lk  = t & 15, lm = t >> 4;   // A loads
  const int ln  = t & 63, lkq = t >> 6;  // B loads
  const int tn  = t & 15, tm = t >> 4;   // compute
  const int kBegin = blockIdx.z * kSpan;
  const int kEnd   = kBegin + kSpan;
  float* C = Cm + (size_t)blockIdx.z * cStride;
  float acc[4][4] = {};
  for (int k0 = kBegin; k0 < kEnd; k0 += 16) {
    {
      int gk = k0 + lk;
#pragma unroll
      for (int j = 0; j < 4; ++j) {
        int m = lm + 16 * j, gm = bm + m;
        As[lk][m] = (gm < M) ? A[(size_t)gm * K + gk] : 0.f;
      }
    }
    {
      int gn = bn + ln;
#pragma unroll
      for (int j = 0; j < 4; ++j) {
        int k = lkq + 4 * j;
        Bs[k][ln] = (gn < N) ? Bm[(size_t)(k0 + k) * N + gn] : 0.f;
      }
    }
    __syncthreads();
#pragma unroll
    for (int k = 0; k < 16; ++k) {
      float4 av = *(const float4*)&As[k][tm * 4];
      float4 bv = *(const float4*)&Bs[k][tn * 4];
      float a[4] = {av.x, av.y, av.z, av.w};
      float bb[4] = {bv.x, bv.y, bv.z, bv.w};
#pragma unroll
      for (int i2 = 0; i2 < 4; ++i2)
#pragma unroll
        for (int j2 = 0; j2 < 4; ++j2)
          acc[i2][j2] += a[i2] * bb[j2];
    }
    __syncthreads();
  }
#pragma unroll
  for (int i2 = 0; i2 < 4; ++i2) {
    int gm = bm + tm * 4 + i2;
    if (gm >= M) continue;
#pragma unroll
    for (int j2 = 0; j2 < 4; ++j2) {
      int gn = bn + tn * 4 + j2;
      if (gn < N) C[(size_t)gm * N + gn] = acc[i2][j2] * scale;
    }
  }
}

// ---------------- reduce split-K partials: psi2 = sum_s parts[s] / 192 ----------------
__global__ __launch_bounds__(THREADS) void k_reduce_psi2(
    const float* __restrict__ parts, float* __restrict__ psi2) {
  int idx = blockIdx.x * THREADS + threadIdx.x;
  if (idx >= F_SO3 * SO3_DIM) return;
  float acc = 0.f;
#pragma unroll
  for (int s = 0; s < 8; ++s) acc += parts[(size_t)s * (F_SO3 * SO3_DIM) + idx];
  psi2[idx] = acc * (1.0f / 192.0f);  // 1/sqrt(36864)
}

// ---------------- stage F: out[b, off+v*d+m] = sum_{f,u} z2[b,f,off+u*d+m]*psi2[f,off+v*d+u] / sqrt(300d) ----------------
__global__ __launch_bounds__(THREADS) void k_stage_f(
    const float* __restrict__ z2, const float* __restrict__ psi2, float* __restrict__ out) {
  const int b = blockIdx.x / 9;
  const int l = blockIdx.x % 9;
  const int d = 2 * l + 1, d2 = d * d;
  const int off = d_SO3_OFF[l];
  __shared__ float zb[10][289];
  __shared__ float pb[10][289];
  const int tid = threadIdx.x;
  float acc[2] = {0.f, 0.f};
  const float scale = rsqrtf(300.0f * (float)d);
  for (int fc = 0; fc < F_SO3; fc += 10) {
    for (int t = tid; t < 10 * d2; t += THREADS) {
      int fl = t / d2, q = t - fl * d2;
      int f  = fc + fl;
      zb[fl][q] = z2[((size_t)b * F_SO3 + f) * SO3_DIM + off + q];
      pb[fl][q] = psi2[(size_t)f * SO3_DIM + off + q];
    }
    __syncthreads();
#pragma unroll 2
    for (int io = 0; io < 2; ++io) {
      int i = tid + io * THREADS;
      if (i < d2) {
        int v = i / d, m = i - v * d;
        float a = acc[io];
#pragma unroll
        for (int fl = 0; fl < 10; ++fl) {
          float s_ = 0.f;
          for (int u = 0; u < d; ++u)
            s_ += zb[fl][u * d + m] * pb[fl][v * d + u];
          a += s_;
        }
        acc[io] = a;
      }
    }
    __syncthreads();
  }
  for (int io = 0; io < 2; ++io) {
    int i = tid + io * THREADS;
    if (i < d2) out[(size_t)b * SO3_DIM + off + i] = acc[io] * scale;
  }
}

// ---------------- launch ----------------
extern "C" void kernel_launch(void* const* d_in, const int* in_sizes, int n_in,
                              void* d_out, int out_size, void* d_ws, size_t ws_size,
                              hipStream_t stream) {
  const float* x     = (const float*)d_in[0];
  const float* Fm    = (const float*)d_in[1];
  const float* w_s2  = (const float*)d_in[2];
  const float* Y     = (const float*)d_in[3];
  const float* w_so3 = (const float*)d_in[4];
  const float* D     = (const float*)d_in[5];
  const float* D_act = (const float*)d_in[6];
  float* out = (float*)d_out;
  float* ws  = (float*)d_ws;

  float* y    = ws + WS_Y;
  float* psi  = ws + WS_PSI;
  float* z    = ws + WS_Z;
  float* s    = ws + WS_S;
  float* z2   = ws + WS_Z2;
  float* p2p  = ws + WS_P2P;
  float* psi2 = ws + WS_PSI2;

  // A: y = F . x   (memory-bound, 987 MB read)
  k_stage_a<<<NPAIR / 9, THREADS, 0, stream>>>(Fm, x, y);
  // B: psi
  k_psi<<<(F_IN * F_SO3 * S2_DIM + THREADS - 1) / THREADS, THREADS, 0, stream>>>(w_s2, Y, psi);
  // C: z (per-l mixing)
  k_stage_c<<<B_ * F_SO3, THREADS, 0, stream>>>(y, psi, z);
  // D1: s = relu(z @ D_act^T)   M=2400 N=4096 K=969
  k_gemm_nt_relu<<<dim3(G_ACT / 64, (B_ * F_SO3 + 63) / 64), THREADS, 0, stream>>>(
      z, D_act, s, B_ * F_SO3, G_ACT, SO3_DIM);
  // D2: z2 = s @ D_act / 4096   M=2400 N=969 K=4096
  k_gemm_nn<<<dim3((SO3_DIM + 63) / 64, (B_ * F_SO3 + 63) / 64, 1), THREADS, 0, stream>>>(
      s, D_act, z2, B_ * F_SO3, SO3_DIM, G_ACT, G_ACT, 1.0f / G_ACT, 0);
  // E1: psi2 partials = w_so3 @ D  (split-K 8)   M=300 N=969 K=36864
  k_gemm_nn<<<dim3((SO3_DIM + 63) / 64, (F_SO3 + 63) / 64, 8), THREADS, 0, stream>>>(
      w_so3, D, p2p, F_SO3, SO3_DIM, G_SO3, G_SO3 / 8, 1.0f, (size_t)F_SO3 * SO3_DIM);
  // E2: reduce partials
  k_reduce_psi2<<<(F_SO3 * SO3_DIM + THREADS - 1) / THREADS, THREADS, 0, stream>>>(p2p, psi2);
  // F: final per-l contraction
  k_stage_f<<<B_ * 9, THREADS, 0, stream>>>(z2, psi2, out);
}

// Round 2
// 847.920 us; speedup vs baseline: 2.5993x; 2.5993x over previous
//
#include <hip/hip_runtime.h>
#include <hip/hip_bf16.h>
#include <math.h>

#define THREADS 256

// ---------------- problem constants ----------------
constexpr int B_    = 8;
constexpr int C_    = 768;
constexpr int KS_   = 7;
constexpr int F_IN  = 81;
constexpr int F_SO3 = 300;
constexpr int S2_DIM  = 81;
constexpr int SO3_DIM = 969;
constexpr int G_S2  = 48;
constexpr int G_ACT = 4096;
constexpr int G_SO3 = 36864;
constexpr int CKK   = C_ * KS_ * KS_;   // 37632
constexpr int CKK4  = CKK / 4;          // 9408
constexpr int NPAIR = F_IN * S2_DIM;    // 6561

__constant__ int d_S2_OFF[10]  = {0, 1, 4, 9, 16, 25, 36, 49, 64, 81};
__constant__ int d_SO3_OFF[10] = {0, 1, 10, 35, 84, 165, 286, 455, 680, 969};

using short8 = __attribute__((ext_vector_type(8))) short;
using f32x4  = __attribute__((ext_vector_type(4))) float;

#define GL16(gp, lp)                                                        \
  __builtin_amdgcn_global_load_lds(                                         \
      (const __attribute__((address_space(1))) void*)(gp),                  \
      (__attribute__((address_space(3))) void*)(lp), 16, 0, 0)

// ---------------- FAST-PATH workspace layout (bytes) ----------------
constexpr size_t AL(size_t x) { return (x + 1023) & ~(size_t)1023; }
constexpr size_t O_Y     = 0;
constexpr size_t O_PSI   = O_Y     + AL((size_t)8 * NPAIR * 4);         // y fp32
constexpr size_t O_ZBF   = O_PSI   + AL((size_t)F_IN * F_SO3 * 81 * 4); // psi fp32
constexpr size_t O_DACT  = O_ZBF   + AL((size_t)2432 * 1024 * 2);       // z bf16 [2432][1024]
constexpr size_t O_DACTT = O_DACT  + AL((size_t)4096 * 1024 * 2);       // D_act bf16 [4096][1024]
constexpr size_t O_WSO3  = O_DACTT + AL((size_t)1024 * 4096 * 2);       // D_act^T bf16 [1024][4096]
constexpr size_t O_DT    = O_WSO3  + AL((size_t)384 * 36864 * 2);       // w_so3 bf16 [384][36864]
constexpr size_t O_SBF   = O_DT    + AL((size_t)1024 * 36864 * 2);      // D^T bf16 [1024][36864]
constexpr size_t O_D2P   = O_SBF   + AL((size_t)2432 * 4096 * 2);       // s bf16 [2432][4096]
constexpr size_t O_Z2P   = O_D2P   + AL((size_t)2 * 2432 * 1024 * 4);   // D2 partials fp32
constexpr size_t O_E1P   = O_Z2P   + AL((size_t)2432 * 1024 * 4);       // z2 fp32 [2432][1024]
constexpr size_t O_PSI2  = O_E1P   + AL((size_t)16 * 384 * 1024 * 4);   // E1 partials fp32
constexpr size_t FAST_NEED = O_PSI2 + AL((size_t)F_SO3 * SO3_DIM * 4);

// ---------------- FALLBACK workspace layout (floats, round-1) ----------------
constexpr size_t WS_Y    = 0;
constexpr size_t WS_PSI  = 52488;
constexpr size_t WS_Z    = 2020788;
constexpr size_t WS_S    = 4346388;
constexpr size_t WS_Z2   = 14176788;
constexpr size_t WS_P2P  = 16502388;
constexpr size_t WS_PSI2 = 18827988;

// ================= stage A: y[b,f,s] = dot(F[f,s,:], x[b,:]) =================
__global__ __launch_bounds__(THREADS) void k_stage_a(
    const float* __restrict__ Fm, const float* __restrict__ x, float* __restrict__ y) {
  const int p0  = blockIdx.x * 9;
  const int tid = threadIdx.x;
  const float4* __restrict__ F4 = (const float4*)Fm;
  const float4* __restrict__ x4 = (const float4*)x;

  float acc[9][8];
#pragma unroll
  for (int p = 0; p < 9; ++p)
#pragma unroll
    for (int b = 0; b < 8; ++b) acc[p][b] = 0.f;

  for (int i = tid; i < CKK4; i += THREADS) {
    float4 xv[8];
#pragma unroll
    for (int b = 0; b < 8; ++b) xv[b] = x4[b * CKK4 + i];
#pragma unroll
    for (int p = 0; p < 9; ++p) {
      float4 fv = F4[(size_t)(p0 + p) * CKK4 + i];
#pragma unroll
      for (int b = 0; b < 8; ++b)
        acc[p][b] += fv.x * xv[b].x + fv.y * xv[b].y + fv.z * xv[b].z + fv.w * xv[b].w;
    }
  }

  __shared__ float red[4][72];
  const int lane = tid & 63, wid = tid >> 6;
#pragma unroll
  for (int p = 0; p < 9; ++p) {
#pragma unroll
    for (int b = 0; b < 8; ++b) {
      float v = acc[p][b];
      v += __shfl_down(v, 32);
      v += __shfl_down(v, 16);
      v += __shfl_down(v, 8);
      v += __shfl_down(v, 4);
      v += __shfl_down(v, 2);
      v += __shfl_down(v, 1);
      if (lane == 0) red[wid][p * 8 + b] = v;
    }
  }
  __syncthreads();
  if (tid < 72) {
    float v = red[0][tid] + red[1][tid] + red[2][tid] + red[3][tid];
    int p = tid / 8, b = tid % 8;
    y[(size_t)b * NPAIR + p0 + p] = v;
  }
}

// ================= psi[f,g,s] = sum_n w_s2[f,g,n]*Y[n,s] / sqrt(48) =================
__global__ __launch_bounds__(THREADS) void k_psi(
    const float* __restrict__ w_s2, const float* __restrict__ Y, float* __restrict__ psi) {
  int idx = blockIdx.x * THREADS + threadIdx.x;
  if (idx >= F_IN * F_SO3 * S2_DIM) return;
  int s  = idx % S2_DIM;
  int fg = idx / S2_DIM;
  const float* w = w_s2 + (size_t)fg * G_S2;
  float acc = 0.f;
#pragma unroll 8
  for (int n = 0; n < G_S2; ++n) acc += w[n] * Y[n * S2_DIM + s];
  psi[idx] = acc * 0.14433756729740643f;
}

// ================= stage C (bf16 out, padded stride 1024) =================
__global__ __launch_bounds__(THREADS) void k_stage_c_bf(
    const float* __restrict__ y, const float* __restrict__ psi, __hip_bfloat16* __restrict__ z) {
  const int b = blockIdx.x / F_SO3;
  const int g = blockIdx.x % F_SO3;
  __shared__ float ybl[NPAIR];
  __shared__ float psl[NPAIR];
  const int tid = threadIdx.x;
  for (int t = tid; t < NPAIR; t += THREADS) {
    ybl[t] = y[(size_t)b * NPAIR + t];
    int f = t / S2_DIM, s = t % S2_DIM;
    psl[t] = psi[((size_t)f * F_SO3 + g) * S2_DIM + s];
  }
  __syncthreads();
  for (int i = tid; i < 1024; i += THREADS) {
    float acc = 0.f;
    if (i < SO3_DIM) {
      int l = 0;
      while (i >= d_SO3_OFF[l + 1]) ++l;
      int d  = 2 * l + 1;
      int r  = i - d_SO3_OFF[l];
      int u  = r / d, m = r - u * d;
      int so = d_S2_OFF[l];
#pragma unroll 9
      for (int f = 0; f < F_IN; ++f)
        acc += ybl[f * S2_DIM + so + m] * psl[f * S2_DIM + so + u];
      acc *= (1.0f / 9.0f);
    }
    z[((size_t)b * F_SO3 + g) * 1024 + i] = __float2bfloat16(acc);
  }
}

// ================= stage C (fp32 out, round-1 fallback) =================
__global__ __launch_bounds__(THREADS) void k_stage_c(
    const float* __restrict__ y, const float* __restrict__ psi, float* __restrict__ z) {
  const int b = blockIdx.x / F_SO3;
  const int g = blockIdx.x % F_SO3;
  __shared__ float ybl[NPAIR];
  __shared__ float psl[NPAIR];
  const int tid = threadIdx.x;
  for (int t = tid; t < NPAIR; t += THREADS) {
    ybl[t] = y[(size_t)b * NPAIR + t];
    int f = t / S2_DIM, s = t % S2_DIM;
    psl[t] = psi[((size_t)f * F_SO3 + g) * S2_DIM + s];
  }
  __syncthreads();
  for (int i = tid; i < SO3_DIM; i += THREADS) {
    int l = 0;
    while (i >= d_SO3_OFF[l + 1]) ++l;
    int d  = 2 * l + 1;
    int r  = i - d_SO3_OFF[l];
    int u  = r / d, m = r - u * d;
    int so = d_S2_OFF[l];
    float acc = 0.f;
#pragma unroll 9
    for (int f = 0; f < F_IN; ++f)
      acc += ybl[f * S2_DIM + so + m] * psl[f * S2_DIM + so + u];
    z[((size_t)b * F_SO3 + g) * SO3_DIM + i] = acc * (1.0f / 9.0f);
  }
}

// ================= fp32 -> bf16 pad copy =================
__global__ __launch_bounds__(THREADS) void k_cvt_pad(
    const float* __restrict__ src, __hip_bfloat16* __restrict__ dst,
    int R, int Cs, int Cp, int Rp) {
  size_t idx = (size_t)blockIdx.x * THREADS + threadIdx.x;
  size_t total = (size_t)Rp * Cp;
  if (idx >= total) return;
  int r = (int)(idx / Cp), c = (int)(idx % Cp);
  float v = (r < R && c < Cs) ? src[(size_t)r * Cs + c] : 0.f;
  dst[idx] = __float2bfloat16(v);
}

// ================= fp32 [R][Cs] -> bf16 transpose dst[c][r] =================
__global__ __launch_bounds__(THREADS) void k_transpose_cvt(
    const float* __restrict__ src, __hip_bfloat16* __restrict__ dst,
    int R, int Cs, size_t dstStride) {
  __shared__ float tile[32][33];
  const int c0 = blockIdx.x * 32, r0 = blockIdx.y * 32;
  const int tx = threadIdx.x & 31, ty = threadIdx.x >> 5;  // 32 x 8
#pragma unroll
  for (int i = 0; i < 32; i += 8) {
    int r = r0 + ty + i, c = c0 + tx;
    tile[ty + i][tx] = (r < R && c < Cs) ? src[(size_t)r * Cs + c] : 0.f;
  }
  __syncthreads();
#pragma unroll
  for (int i = 0; i < 32; i += 8) {
    int c = c0 + ty + i, r = r0 + tx;
    if (c < Cs && r < R) dst[(size_t)c * dstStride + r] = __float2bfloat16(tile[tx][ty + i]);
  }
}

// ================= bf16 MFMA GEMM, NT: C = scale*(A @ B^T) =================
// A: [Mp][K] bf16 rows K-contig; B: [Np][K] bf16 rows K-contig.
// Mp,Np multiples of 128; K,kSpan multiples of 64. grid=(Np/128, Mp/128, splits).
// EPI 0: fp32 out (+ split offset); EPI 1: bf16 out with relu.
template <int EPI>
__global__ __launch_bounds__(THREADS) void k_mfma_nt(
    const __hip_bfloat16* __restrict__ A, const __hip_bfloat16* __restrict__ B,
    void* __restrict__ Cout, int K, int kSpan, int Ncols, float scale, size_t splitStride) {
  __shared__ __align__(16) char smem[32768];
  char* As = smem;
  char* Bs = smem + 16384;

  const int t    = threadIdx.x;
  const int lane = t & 63;
  const int wave = t >> 6;
  const int wr   = wave >> 1, wc = wave & 1;
  const int bm = blockIdx.y * 128, bn = blockIdx.x * 128;
  const int kBegin = blockIdx.z * kSpan;
  const int kEnd   = kBegin + kSpan;

  // staging addresses: chunk i covers lds bytes [i*4096 + t*16, +16)
  const char* pA[4];
  const char* pB[4];
  int ldsOff[4];
#pragma unroll
  for (int i = 0; i < 4; ++i) {
    int L   = i * 4096 + t * 16;
    int row = L >> 7;          // 128 B per row (64 bf16)
    int kb  = (L & 127) ^ ((row & 7) << 4);  // inverse-swizzled source column
    pA[i] = (const char*)A + ((size_t)(bm + row) * K) * 2 + kb;
    pB[i] = (const char*)B + ((size_t)(bn + row) * K) * 2 + kb;
    ldsOff[i] = L;
  }

  f32x4 acc[4][4] = {};

  for (int k0 = kBegin; k0 < kEnd; k0 += 64) {
    size_t koff = (size_t)k0 * 2;
#pragma unroll
    for (int i = 0; i < 4; ++i) {
      GL16(pA[i] + koff, As + ldsOff[i]);
      GL16(pB[i] + koff, Bs + ldsOff[i]);
    }
    __syncthreads();
#pragma unroll
    for (int kk = 0; kk < 2; ++kk) {
      const int klin = kk * 64 + ((lane >> 4) << 4);
      short8 af[4], bfr[4];
#pragma unroll
      for (int m = 0; m < 4; ++m) {
        int ra = (wr << 6) + (m << 4) + (lane & 15);
        af[m] = *(const short8*)(As + ra * 128 + (klin ^ ((ra & 7) << 4)));
        int rb = (wc << 6) + (m << 4) + (lane & 15);
        bfr[m] = *(const short8*)(Bs + rb * 128 + (klin ^ ((rb & 7) << 4)));
      }
#pragma unroll
      for (int m = 0; m < 4; ++m)
#pragma unroll
        for (int n = 0; n < 4; ++n)
          acc[m][n] = __builtin_amdgcn_mfma_f32_16x16x32_bf16(af[m], bfr[n], acc[m][n], 0, 0, 0);
    }
    __syncthreads();
  }

  const int rbase = bm + (wr << 6) + ((lane >> 4) << 2);
  const int cbase = bn + (wc << 6) + (lane & 15);
  if (EPI == 0) {
    float* C = (float*)Cout + (size_t)blockIdx.z * splitStride;
#pragma unroll
    for (int m = 0; m < 4; ++m)
#pragma unroll
      for (int n = 0; n < 4; ++n)
#pragma unroll
        for (int r = 0; r < 4; ++r)
          C[(size_t)(rbase + m * 16 + r) * Ncols + (cbase + n * 16)] = acc[m][n][r] * scale;
  } else {
    __hip_bfloat16* C = (__hip_bfloat16*)Cout;
#pragma unroll
    for (int m = 0; m < 4; ++m)
#pragma unroll
      for (int n = 0; n < 4; ++n)
#pragma unroll
        for (int r = 0; r < 4; ++r)
          C[(size_t)(rbase + m * 16 + r) * Ncols + (cbase + n * 16)] =
              __float2bfloat16(fmaxf(acc[m][n][r], 0.f));
  }
}

// ================= reduce split-K partials =================
__global__ __launch_bounds__(THREADS) void k_reduce_split(
    const float* __restrict__ parts, float* __restrict__ dst, int R, int C,
    size_t rowStride, size_t splitStride, size_t dstStride, int nSplit, float scale) {
  int idx = blockIdx.x * THREADS + threadIdx.x;
  if (idx >= R * C) return;
  int r = idx / C, c = idx % C;
  float a = 0.f;
  for (int s = 0; s < nSplit; ++s) a += parts[(size_t)s * splitStride + (size_t)r * rowStride + c];
  dst[(size_t)r * dstStride + c] = a * scale;
}

// ================= fallback fp32 GEMMs (round-1) =================
__global__ __launch_bounds__(THREADS) void k_gemm_nt_relu(
    const float* __restrict__ A, const float* __restrict__ Bm, float* __restrict__ Cm,
    int M, int N, int K) {
  __shared__ float As[16][68];
  __shared__ float Bs[16][68];
  const int bm = blockIdx.y * 64, bn = blockIdx.x * 64;
  const int t  = threadIdx.x;
  const int lk = t & 15, lm = t >> 4;
  const int tn = t & 15, tm = t >> 4;
  float acc[4][4] = {};
  for (int k0 = 0; k0 < K; k0 += 16) {
    int gk = k0 + lk;
#pragma unroll
    for (int j = 0; j < 4; ++j) {
      int m  = lm + 16 * j;
      int gm = bm + m;
      As[lk][m] = (gm < M && gk < K) ? A[(size_t)gm * K + gk] : 0.f;
      int gn = bn + m;
      Bs[lk][m] = (gn < N && gk < K) ? Bm[(size_t)gn * K + gk] : 0.f;
    }
    __syncthreads();
#pragma unroll
    for (int k = 0; k < 16; ++k) {
      float4 av = *(const float4*)&As[k][tm * 4];
      float4 bv = *(const float4*)&Bs[k][tn * 4];
      float a[4] = {av.x, av.y, av.z, av.w};
      float bb[4] = {bv.x, bv.y, bv.z, bv.w};
#pragma unroll
      for (int i2 = 0; i2 < 4; ++i2)
#pragma unroll
        for (int j2 = 0; j2 < 4; ++j2)
          acc[i2][j2] += a[i2] * bb[j2];
    }
    __syncthreads();
  }
#pragma unroll
  for (int i2 = 0; i2 < 4; ++i2) {
    int gm = bm + tm * 4 + i2;
    if (gm >= M) continue;
#pragma unroll
    for (int j2 = 0; j2 < 4; ++j2) {
      int gn = bn + tn * 4 + j2;
      if (gn < N) Cm[(size_t)gm * N + gn] = fmaxf(acc[i2][j2], 0.f);
    }
  }
}

__global__ __launch_bounds__(THREADS) void k_gemm_nn(
    const float* __restrict__ A, const float* __restrict__ Bm, float* __restrict__ Cm,
    int M, int N, int K, int kSpan, float scale, size_t cStride) {
  __shared__ float As[16][68];
  __shared__ float Bs[16][68];
  const int bm = blockIdx.y * 64, bn = blockIdx.x * 64;
  const int t   = threadIdx.x;
  const int lk  = t & 15, lm = t >> 4;
  const int ln  = t & 63, lkq = t >> 6;
  const int tn  = t & 15, tm = t >> 4;
  const int kBegin = blockIdx.z * kSpan;
  const int kEnd   = kBegin + kSpan;
  float* C = Cm + (size_t)blockIdx.z * cStride;
  float acc[4][4] = {};
  for (int k0 = kBegin; k0 < kEnd; k0 += 16) {
    {
      int gk = k0 + lk;
#pragma unroll
      for (int j = 0; j < 4; ++j) {
        int m = lm + 16 * j, gm = bm + m;
        As[lk][m] = (gm < M) ? A[(size_t)gm * K + gk] : 0.f;
      }
    }
    {
      int gn = bn + ln;
#pragma unroll
      for (int j = 0; j < 4; ++j) {
        int k = lkq + 4 * j;
        Bs[k][ln] = (gn < N) ? Bm[(size_t)(k0 + k) * N + gn] : 0.f;
      }
    }
    __syncthreads();
#pragma unroll
    for (int k = 0; k < 16; ++k) {
      float4 av = *(const float4*)&As[k][tm * 4];
      float4 bv = *(const float4*)&Bs[k][tn * 4];
      float a[4] = {av.x, av.y, av.z, av.w};
      float bb[4] = {bv.x, bv.y, bv.z, bv.w};
#pragma unroll
      for (int i2 = 0; i2 < 4; ++i2)
#pragma unroll
        for (int j2 = 0; j2 < 4; ++j2)
          acc[i2][j2] += a[i2] * bb[j2];
    }
    __syncthreads();
  }
#pragma unroll
  for (int i2 = 0; i2 < 4; ++i2) {
    int gm = bm + tm * 4 + i2;
    if (gm >= M) continue;
#pragma unroll
    for (int j2 = 0; j2 < 4; ++j2) {
      int gn = bn + tn * 4 + j2;
      if (gn < N) C[(size_t)gm * N + gn] = acc[i2][j2] * scale;
    }
  }
}

__global__ __launch_bounds__(THREADS) void k_reduce_psi2(
    const float* __restrict__ parts, float* __restrict__ psi2) {
  int idx = blockIdx.x * THREADS + threadIdx.x;
  if (idx >= F_SO3 * SO3_DIM) return;
  float acc = 0.f;
#pragma unroll
  for (int s = 0; s < 8; ++s) acc += parts[(size_t)s * (F_SO3 * SO3_DIM) + idx];
  psi2[idx] = acc * (1.0f / 192.0f);
}

// ================= stage F =================
__global__ __launch_bounds__(THREADS) void k_stage_f(
    const float* __restrict__ z2, const float* __restrict__ psi2, float* __restrict__ out,
    int zStride) {
  const int b = blockIdx.x / 9;
  const int l = blockIdx.x % 9;
  const int d = 2 * l + 1, d2 = d * d;
  const int off = d_SO3_OFF[l];
  __shared__ float zb[10][289];
  __shared__ float pb[10][289];
  const int tid = threadIdx.x;
  float acc[2] = {0.f, 0.f};
  const float scale = rsqrtf(300.0f * (float)d);
  for (int fc = 0; fc < F_SO3; fc += 10) {
    for (int t = tid; t < 10 * d2; t += THREADS) {
      int fl = t / d2, q = t - fl * d2;
      int f  = fc + fl;
      zb[fl][q] = z2[((size_t)b * F_SO3 + f) * zStride + off + q];
      pb[fl][q] = psi2[(size_t)f * SO3_DIM + off + q];
    }
    __syncthreads();
#pragma unroll 2
    for (int io = 0; io < 2; ++io) {
      int i = tid + io * THREADS;
      if (i < d2) {
        int v = i / d, m = i - v * d;
        float a = acc[io];
#pragma unroll
        for (int fl = 0; fl < 10; ++fl) {
          float s_ = 0.f;
          for (int u = 0; u < d; ++u)
            s_ += zb[fl][u * d + m] * pb[fl][v * d + u];
          a += s_;
        }
        acc[io] = a;
      }
    }
    __syncthreads();
  }
  for (int io = 0; io < 2; ++io) {
    int i = tid + io * THREADS;
    if (i < d2) out[(size_t)b * SO3_DIM + off + i] = acc[io] * scale;
  }
}

// ================= launch =================
extern "C" void kernel_launch(void* const* d_in, const int* in_sizes, int n_in,
                              void* d_out, int out_size, void* d_ws, size_t ws_size,
                              hipStream_t stream) {
  const float* x     = (const float*)d_in[0];
  const float* Fm    = (const float*)d_in[1];
  const float* w_s2  = (const float*)d_in[2];
  const float* Y     = (const float*)d_in[3];
  const float* w_so3 = (const float*)d_in[4];
  const float* D     = (const float*)d_in[5];
  const float* D_act = (const float*)d_in[6];
  float* out = (float*)d_out;

  if (ws_size >= FAST_NEED) {
    char* p = (char*)d_ws;
    float*          y       = (float*)(p + O_Y);
    float*          psi     = (float*)(p + O_PSI);
    __hip_bfloat16* z_bf    = (__hip_bfloat16*)(p + O_ZBF);
    __hip_bfloat16* Dact_bf = (__hip_bfloat16*)(p + O_DACT);
    __hip_bfloat16* DactT_bf= (__hip_bfloat16*)(p + O_DACTT);
    __hip_bfloat16* wso3_bf = (__hip_bfloat16*)(p + O_WSO3);
    __hip_bfloat16* DT_bf   = (__hip_bfloat16*)(p + O_DT);
    __hip_bfloat16* s_bf    = (__hip_bfloat16*)(p + O_SBF);
    float*          d2p     = (float*)(p + O_D2P);
    float*          z2p     = (float*)(p + O_Z2P);
    float*          e1p     = (float*)(p + O_E1P);
    float*          psi2    = (float*)(p + O_PSI2);

    // operand conversions (independent of stage A/C)
    k_cvt_pad<<<(4096 * 1024 + THREADS - 1) / THREADS, THREADS, 0, stream>>>(
        D_act, Dact_bf, G_ACT, SO3_DIM, 1024, 4096);
    k_transpose_cvt<<<dim3(31, 128), THREADS, 0, stream>>>(D_act, DactT_bf, G_ACT, SO3_DIM, 4096);
    k_cvt_pad<<<(384 * 36864 + THREADS - 1) / THREADS, THREADS, 0, stream>>>(
        w_so3, wso3_bf, F_SO3, G_SO3, G_SO3, 384);
    k_transpose_cvt<<<dim3(31, 1152), THREADS, 0, stream>>>(D, DT_bf, G_SO3, SO3_DIM, 36864);

    // A, B, C stages
    k_stage_a<<<NPAIR / 9, THREADS, 0, stream>>>(Fm, x, y);
    k_psi<<<(F_IN * F_SO3 * S2_DIM + THREADS - 1) / THREADS, THREADS, 0, stream>>>(w_s2, Y, psi);
    k_stage_c_bf<<<B_ * F_SO3, THREADS, 0, stream>>>(y, psi, z_bf);

    // D1: s = relu(z @ D_act^T), bf16 out. M=2432 N=4096 K=1024
    k_mfma_nt<1><<<dim3(32, 19, 1), THREADS, 0, stream>>>(
        z_bf, Dact_bf, s_bf, 1024, 1024, 4096, 1.f, 0);
    // D2: z2 = s @ D_act / 4096. M=2432 N=1024 K=4096, split-K 2
    k_mfma_nt<0><<<dim3(8, 19, 2), THREADS, 0, stream>>>(
        s_bf, DactT_bf, d2p, 4096, 2048, 1024, 1.f, (size_t)2432 * 1024);
    k_reduce_split<<<(2400 * 969 + THREADS - 1) / THREADS, THREADS, 0, stream>>>(
        d2p, z2p, 2400, 969, 1024, (size_t)2432 * 1024, 1024, 2, 1.0f / G_ACT);
    // E1: psi2 = w_so3 @ D / 192. M=384 N=1024 K=36864, split-K 16
    k_mfma_nt<0><<<dim3(8, 3, 16), THREADS, 0, stream>>>(
        wso3_bf, DT_bf, e1p, G_SO3, 2304, 1024, 1.f, (size_t)384 * 1024);
    k_reduce_split<<<(300 * 969 + THREADS - 1) / THREADS, THREADS, 0, stream>>>(
        e1p, psi2, 300, 969, 1024, (size_t)384 * 1024, 969, 16, 1.0f / 192.0f);

    // F: final per-l contraction
    k_stage_f<<<B_ * 9, THREADS, 0, stream>>>(z2p, psi2, out, 1024);
  } else {
    float* ws  = (float*)d_ws;
    float* y    = ws + WS_Y;
    float* psi  = ws + WS_PSI;
    float* z    = ws + WS_Z;
    float* s    = ws + WS_S;
    float* z2   = ws + WS_Z2;
    float* p2p  = ws + WS_P2P;
    float* psi2 = ws + WS_PSI2;

    k_stage_a<<<NPAIR / 9, THREADS, 0, stream>>>(Fm, x, y);
    k_psi<<<(F_IN * F_SO3 * S2_DIM + THREADS - 1) / THREADS, THREADS, 0, stream>>>(w_s2, Y, psi);
    k_stage_c<<<B_ * F_SO3, THREADS, 0, stream>>>(y, psi, z);
    k_gemm_nt_relu<<<dim3(G_ACT / 64, (B_ * F_SO3 + 63) / 64), THREADS, 0, stream>>>(
        z, D_act, s, B_ * F_SO3, G_ACT, SO3_DIM);
    k_gemm_nn<<<dim3((SO3_DIM + 63) / 64, (B_ * F_SO3 + 63) / 64, 1), THREADS, 0, stream>>>(
        s, D_act, z2, B_ * F_SO3, SO3_DIM, G_ACT, G_ACT, 1.0f / G_ACT, 0);
    k_gemm_nn<<<dim3((SO3_DIM + 63) / 64, (F_SO3 + 63) / 64, 8), THREADS, 0, stream>>>(
        w_so3, D, p2p, F_SO3, SO3_DIM, G_SO3, G_SO3 / 8, 1.0f, (size_t)F_SO3 * SO3_DIM);
    k_reduce_psi2<<<(F_SO3 * SO3_DIM + THREADS - 1) / THREADS, THREADS, 0, stream>>>(p2p, psi2);
    k_stage_f<<<B_ * 9, THREADS, 0, stream>>>(z2, psi2, out, SO3_DIM);
  }
}

// Round 3
// 642.843 us; speedup vs baseline: 3.4285x; 1.3190x over previous
//
#include <hip/hip_runtime.h>
#include <hip/hip_bf16.h>
#include <math.h>

#define THREADS 256

// ---------------- problem constants ----------------
constexpr int B_    = 8;
constexpr int C_    = 768;
constexpr int KS_   = 7;
constexpr int F_IN  = 81;
constexpr int F_SO3 = 300;
constexpr int S2_DIM  = 81;
constexpr int SO3_DIM = 969;
constexpr int G_S2  = 48;
constexpr int G_ACT = 4096;
constexpr int G_SO3 = 36864;
constexpr int CKK   = C_ * KS_ * KS_;   // 37632
constexpr int CKK4  = CKK / 4;          // 9408
constexpr int NPAIR = F_IN * S2_DIM;    // 6561

constexpr int D2_SPLIT = 4;
constexpr int E1_SPLIT = 32;
constexpr int F_SPLIT  = 5;   // 300 / 60

__constant__ int d_S2_OFF[10]  = {0, 1, 4, 9, 16, 25, 36, 49, 64, 81};
__constant__ int d_SO3_OFF[10] = {0, 1, 10, 35, 84, 165, 286, 455, 680, 969};

using short8 = __attribute__((ext_vector_type(8))) short;
using f32x4  = __attribute__((ext_vector_type(4))) float;

#define GL16(gp, lp)                                                        \
  __builtin_amdgcn_global_load_lds(                                         \
      (const __attribute__((address_space(1))) void*)(gp),                  \
      (__attribute__((address_space(3))) void*)(lp), 16, 0, 0)

// ---------------- FAST-PATH workspace layout (bytes) ----------------
constexpr size_t AL(size_t x) { return (x + 1023) & ~(size_t)1023; }
constexpr size_t O_Y     = 0;
constexpr size_t O_PSI   = O_Y     + AL((size_t)8 * NPAIR * 4);
constexpr size_t O_ZBF   = O_PSI   + AL((size_t)F_IN * F_SO3 * 81 * 4);
constexpr size_t O_DACT  = O_ZBF   + AL((size_t)2432 * 1024 * 2);
constexpr size_t O_DACTT = O_DACT  + AL((size_t)4096 * 1024 * 2);
constexpr size_t O_WSO3  = O_DACTT + AL((size_t)1024 * 4096 * 2);
constexpr size_t O_DT    = O_WSO3  + AL((size_t)384 * 36864 * 2);
constexpr size_t O_SBF   = O_DT    + AL((size_t)1024 * 36864 * 2);
constexpr size_t O_D2P   = O_SBF   + AL((size_t)2432 * 4096 * 2);
constexpr size_t O_Z2P   = O_D2P   + AL((size_t)D2_SPLIT * 2432 * 1024 * 4);
constexpr size_t O_E1P   = O_Z2P   + AL((size_t)2432 * 1024 * 4);
constexpr size_t O_PSI2  = O_E1P   + AL((size_t)E1_SPLIT * 384 * 1024 * 4);
constexpr size_t O_SFP   = O_PSI2  + AL((size_t)F_SO3 * SO3_DIM * 4);
constexpr size_t FAST_NEED = O_SFP + AL((size_t)F_SPLIT * 8 * SO3_DIM * 4);

// ---------------- FALLBACK workspace layout (floats, round-1) ----------------
constexpr size_t WS_Y    = 0;
constexpr size_t WS_PSI  = 52488;
constexpr size_t WS_Z    = 2020788;
constexpr size_t WS_S    = 4346388;
constexpr size_t WS_Z2   = 14176788;
constexpr size_t WS_P2P  = 16502388;
constexpr size_t WS_PSI2 = 18827988;

// ================= stage A: y[b,f,s] = dot(F[f,s,:], x[b,:]) =================
// 2187 blocks x 3 pairs: ~8.5 waves/SIMD for latency hiding.
__global__ __launch_bounds__(THREADS) void k_stage_a3(
    const float* __restrict__ Fm, const float* __restrict__ x, float* __restrict__ y) {
  const int p0  = blockIdx.x * 3;
  const int tid = threadIdx.x;
  const float4* __restrict__ F4 = (const float4*)Fm;
  const float4* __restrict__ x4 = (const float4*)x;

  float acc[3][8];
#pragma unroll
  for (int p = 0; p < 3; ++p)
#pragma unroll
    for (int b = 0; b < 8; ++b) acc[p][b] = 0.f;

  for (int i = tid; i < CKK4; i += THREADS) {
    float4 xv[8];
#pragma unroll
    for (int b = 0; b < 8; ++b) xv[b] = x4[b * CKK4 + i];
#pragma unroll
    for (int p = 0; p < 3; ++p) {
      float4 fv = F4[(size_t)(p0 + p) * CKK4 + i];
#pragma unroll
      for (int b = 0; b < 8; ++b)
        acc[p][b] += fv.x * xv[b].x + fv.y * xv[b].y + fv.z * xv[b].z + fv.w * xv[b].w;
    }
  }

  __shared__ float red[4][24];
  const int lane = tid & 63, wid = tid >> 6;
#pragma unroll
  for (int p = 0; p < 3; ++p) {
#pragma unroll
    for (int b = 0; b < 8; ++b) {
      float v = acc[p][b];
      v += __shfl_down(v, 32);
      v += __shfl_down(v, 16);
      v += __shfl_down(v, 8);
      v += __shfl_down(v, 4);
      v += __shfl_down(v, 2);
      v += __shfl_down(v, 1);
      if (lane == 0) red[wid][p * 8 + b] = v;
    }
  }
  __syncthreads();
  if (tid < 24) {
    float v = red[0][tid] + red[1][tid] + red[2][tid] + red[3][tid];
    int p = tid / 8, b = tid % 8;
    y[(size_t)b * NPAIR + p0 + p] = v;
  }
}

// ================= psi[f,g,s] = sum_n w_s2[f,g,n]*Y[n,s] / sqrt(48) =================
__global__ __launch_bounds__(THREADS) void k_psi(
    const float* __restrict__ w_s2, const float* __restrict__ Y, float* __restrict__ psi) {
  int idx = blockIdx.x * THREADS + threadIdx.x;
  if (idx >= F_IN * F_SO3 * S2_DIM) return;
  int s  = idx % S2_DIM;
  int fg = idx / S2_DIM;
  const float* w = w_s2 + (size_t)fg * G_S2;
  float acc = 0.f;
#pragma unroll 8
  for (int n = 0; n < G_S2; ++n) acc += w[n] * Y[n * S2_DIM + s];
  psi[idx] = acc * 0.14433756729740643f;
}

// ================= stage C (bf16 out, padded stride 1024) =================
__global__ __launch_bounds__(THREADS) void k_stage_c_bf(
    const float* __restrict__ y, const float* __restrict__ psi, __hip_bfloat16* __restrict__ z) {
  const int b = blockIdx.x / F_SO3;
  const int g = blockIdx.x % F_SO3;
  __shared__ float ybl[NPAIR];
  __shared__ float psl[NPAIR];
  const int tid = threadIdx.x;
  for (int t = tid; t < NPAIR; t += THREADS) {
    ybl[t] = y[(size_t)b * NPAIR + t];
    int f = t / S2_DIM, s = t % S2_DIM;
    psl[t] = psi[((size_t)f * F_SO3 + g) * S2_DIM + s];
  }
  __syncthreads();
  for (int i = tid; i < 1024; i += THREADS) {
    float acc = 0.f;
    if (i < SO3_DIM) {
      int l = 0;
      while (i >= d_SO3_OFF[l + 1]) ++l;
      int d  = 2 * l + 1;
      int r  = i - d_SO3_OFF[l];
      int u  = r / d, m = r - u * d;
      int so = d_S2_OFF[l];
#pragma unroll 9
      for (int f = 0; f < F_IN; ++f)
        acc += ybl[f * S2_DIM + so + m] * psl[f * S2_DIM + so + u];
      acc *= (1.0f / 9.0f);
    }
    z[((size_t)b * F_SO3 + g) * 1024 + i] = __float2bfloat16(acc);
  }
}

// ================= stage C (fp32 out, fallback) =================
__global__ __launch_bounds__(THREADS) void k_stage_c(
    const float* __restrict__ y, const float* __restrict__ psi, float* __restrict__ z) {
  const int b = blockIdx.x / F_SO3;
  const int g = blockIdx.x % F_SO3;
  __shared__ float ybl[NPAIR];
  __shared__ float psl[NPAIR];
  const int tid = threadIdx.x;
  for (int t = tid; t < NPAIR; t += THREADS) {
    ybl[t] = y[(size_t)b * NPAIR + t];
    int f = t / S2_DIM, s = t % S2_DIM;
    psl[t] = psi[((size_t)f * F_SO3 + g) * S2_DIM + s];
  }
  __syncthreads();
  for (int i = tid; i < SO3_DIM; i += THREADS) {
    int l = 0;
    while (i >= d_SO3_OFF[l + 1]) ++l;
    int d  = 2 * l + 1;
    int r  = i - d_SO3_OFF[l];
    int u  = r / d, m = r - u * d;
    int so = d_S2_OFF[l];
    float acc = 0.f;
#pragma unroll 9
    for (int f = 0; f < F_IN; ++f)
      acc += ybl[f * S2_DIM + so + m] * psl[f * S2_DIM + so + u];
    z[((size_t)b * F_SO3 + g) * SO3_DIM + i] = acc * (1.0f / 9.0f);
  }
}

// ================= fp32 -> bf16 pad copy =================
__global__ __launch_bounds__(THREADS) void k_cvt_pad(
    const float* __restrict__ src, __hip_bfloat16* __restrict__ dst,
    int R, int Cs, int Cp, int Rp) {
  size_t idx = (size_t)blockIdx.x * THREADS + threadIdx.x;
  size_t total = (size_t)Rp * Cp;
  if (idx >= total) return;
  int r = (int)(idx / Cp), c = (int)(idx % Cp);
  float v = (r < R && c < Cs) ? src[(size_t)r * Cs + c] : 0.f;
  dst[idx] = __float2bfloat16(v);
}

// ================= fp32 [R][Cs] -> bf16 transpose dst[c][r] =================
__global__ __launch_bounds__(THREADS) void k_transpose_cvt(
    const float* __restrict__ src, __hip_bfloat16* __restrict__ dst,
    int R, int Cs, size_t dstStride) {
  __shared__ float tile[32][33];
  const int c0 = blockIdx.x * 32, r0 = blockIdx.y * 32;
  const int tx = threadIdx.x & 31, ty = threadIdx.x >> 5;  // 32 x 8
#pragma unroll
  for (int i = 0; i < 32; i += 8) {
    int r = r0 + ty + i, c = c0 + tx;
    tile[ty + i][tx] = (r < R && c < Cs) ? src[(size_t)r * Cs + c] : 0.f;
  }
  __syncthreads();
#pragma unroll
  for (int i = 0; i < 32; i += 8) {
    int c = c0 + ty + i, r = r0 + tx;
    if (c < Cs && r < R) dst[(size_t)c * dstStride + r] = __float2bfloat16(tile[tx][ty + i]);
  }
}

// ================= bf16 MFMA GEMM, NT: C = scale*(A @ B^T) =================
// A: [Mp][K] bf16 rows K-contig; B: [Np][K] bf16 rows K-contig.
// Mp,Np multiples of 128; K,kSpan multiples of 64.
// grid=(Np/128, Mp/128, splits); bijective XCD-chunk swizzle when nwg%8==0.
// EPI 0: fp32 out (+ split offset); EPI 1: bf16 out with relu.
template <int EPI>
__global__ __launch_bounds__(THREADS) void k_mfma_nt(
    const __hip_bfloat16* __restrict__ A, const __hip_bfloat16* __restrict__ B,
    void* __restrict__ Cout, int K, int kSpan, int Ncols, float scale, size_t splitStride) {
  __shared__ __align__(16) char smem[32768];
  char* As = smem;
  char* Bs = smem + 16384;

  // XCD-aware bijective block remap (m204, r==0 case)
  const int gx = gridDim.x, gy = gridDim.y;
  unsigned nwg = (unsigned)gx * gy * gridDim.z;
  unsigned lin = ((unsigned)blockIdx.z * gy + blockIdx.y) * gx + blockIdx.x;
  if ((nwg & 7u) == 0u) {
    unsigned q = nwg >> 3;
    lin = (lin & 7u) * q + (lin >> 3);
  }
  const int bxi = (int)(lin % (unsigned)gx);
  const unsigned t1 = lin / (unsigned)gx;
  const int byi = (int)(t1 % (unsigned)gy);
  const int bzi = (int)(t1 / (unsigned)gy);

  const int t    = threadIdx.x;
  const int lane = t & 63;
  const int wave = t >> 6;
  const int wr   = wave >> 1, wc = wave & 1;
  const int bm = byi * 128, bn = bxi * 128;
  const int kBegin = bzi * kSpan;
  const int kEnd   = kBegin + kSpan;

  const char* pA[4];
  const char* pB[4];
  int ldsOff[4];
#pragma unroll
  for (int i = 0; i < 4; ++i) {
    int L   = i * 4096 + t * 16;
    int row = L >> 7;                        // 128 B per row (64 bf16)
    int kb  = (L & 127) ^ ((row & 7) << 4);  // inverse-swizzled source column
    pA[i] = (const char*)A + ((size_t)(bm + row) * K) * 2 + kb;
    pB[i] = (const char*)B + ((size_t)(bn + row) * K) * 2 + kb;
    ldsOff[i] = L;
  }

  f32x4 acc[4][4] = {};

  for (int k0 = kBegin; k0 < kEnd; k0 += 64) {
    size_t koff = (size_t)k0 * 2;
#pragma unroll
    for (int i = 0; i < 4; ++i) {
      GL16(pA[i] + koff, As + ldsOff[i]);
      GL16(pB[i] + koff, Bs + ldsOff[i]);
    }
    __syncthreads();
#pragma unroll
    for (int kk = 0; kk < 2; ++kk) {
      const int klin = kk * 64 + ((lane >> 4) << 4);
      short8 af[4], bfr[4];
#pragma unroll
      for (int m = 0; m < 4; ++m) {
        int ra = (wr << 6) + (m << 4) + (lane & 15);
        af[m] = *(const short8*)(As + ra * 128 + (klin ^ ((ra & 7) << 4)));
        int rb = (wc << 6) + (m << 4) + (lane & 15);
        bfr[m] = *(const short8*)(Bs + rb * 128 + (klin ^ ((rb & 7) << 4)));
      }
#pragma unroll
      for (int m = 0; m < 4; ++m)
#pragma unroll
        for (int n = 0; n < 4; ++n)
          acc[m][n] = __builtin_amdgcn_mfma_f32_16x16x32_bf16(af[m], bfr[n], acc[m][n], 0, 0, 0);
    }
    __syncthreads();
  }

  const int rbase = bm + (wr << 6) + ((lane >> 4) << 2);
  const int cbase = bn + (wc << 6) + (lane & 15);
  if (EPI == 0) {
    float* C = (float*)Cout + (size_t)bzi * splitStride;
#pragma unroll
    for (int m = 0; m < 4; ++m)
#pragma unroll
      for (int n = 0; n < 4; ++n)
#pragma unroll
        for (int r = 0; r < 4; ++r)
          C[(size_t)(rbase + m * 16 + r) * Ncols + (cbase + n * 16)] = acc[m][n][r] * scale;
  } else {
    __hip_bfloat16* C = (__hip_bfloat16*)Cout;
#pragma unroll
    for (int m = 0; m < 4; ++m)
#pragma unroll
      for (int n = 0; n < 4; ++n)
#pragma unroll
        for (int r = 0; r < 4; ++r)
          C[(size_t)(rbase + m * 16 + r) * Ncols + (cbase + n * 16)] =
              __float2bfloat16(fmaxf(acc[m][n][r], 0.f));
  }
}

// ================= reduce split-K partials =================
__global__ __launch_bounds__(THREADS) void k_reduce_split(
    const float* __restrict__ parts, float* __restrict__ dst, int R, int C,
    size_t rowStride, size_t splitStride, size_t dstStride, int nSplit, float scale) {
  int idx = blockIdx.x * THREADS + threadIdx.x;
  if (idx >= R * C) return;
  int r = idx / C, c = idx % C;
  float a = 0.f;
  for (int s = 0; s < nSplit; ++s) a += parts[(size_t)s * splitStride + (size_t)r * rowStride + c];
  dst[(size_t)r * dstStride + c] = a * scale;
}

// ================= stage F (split over f), partials =================
__global__ __launch_bounds__(THREADS) void k_stage_f_part(
    const float* __restrict__ z2, const float* __restrict__ psi2, float* __restrict__ partial,
    int zStride) {
  const int b  = blockIdx.x / 9;
  const int l  = blockIdx.x % 9;
  const int sp = blockIdx.y;
  const int d = 2 * l + 1, d2 = d * d;
  const int off = d_SO3_OFF[l];
  __shared__ float zb[10][289];
  __shared__ float pb[10][289];
  const int tid = threadIdx.x;
  float acc[2] = {0.f, 0.f};
  const int fBeg = sp * (F_SO3 / F_SPLIT), fEnd = fBeg + F_SO3 / F_SPLIT;
  for (int fc = fBeg; fc < fEnd; fc += 10) {
    for (int t = tid; t < 10 * d2; t += THREADS) {
      int fl = t / d2, q = t - fl * d2;
      int f  = fc + fl;
      zb[fl][q] = z2[((size_t)b * F_SO3 + f) * zStride + off + q];
      pb[fl][q] = psi2[(size_t)f * SO3_DIM + off + q];
    }
    __syncthreads();
#pragma unroll 2
    for (int io = 0; io < 2; ++io) {
      int i = tid + io * THREADS;
      if (i < d2) {
        int v = i / d, m = i - v * d;
        float a = acc[io];
#pragma unroll
        for (int fl = 0; fl < 10; ++fl) {
          float s_ = 0.f;
          for (int u = 0; u < d; ++u)
            s_ += zb[fl][u * d + m] * pb[fl][v * d + u];
          a += s_;
        }
        acc[io] = a;
      }
    }
    __syncthreads();
  }
  for (int io = 0; io < 2; ++io) {
    int i = tid + io * THREADS;
    if (i < d2) partial[((size_t)sp * 8 + b) * SO3_DIM + off + i] = acc[io];
  }
}

__global__ __launch_bounds__(THREADS) void k_stage_f_red(
    const float* __restrict__ partial, float* __restrict__ out) {
  int idx = blockIdx.x * THREADS + threadIdx.x;
  if (idx >= 8 * SO3_DIM) return;
  int b = idx / SO3_DIM, i = idx % SO3_DIM;
  int l = 0;
  while (i >= d_SO3_OFF[l + 1]) ++l;
  float a = 0.f;
#pragma unroll
  for (int sp = 0; sp < F_SPLIT; ++sp)
    a += partial[((size_t)sp * 8 + b) * SO3_DIM + i];
  out[(size_t)b * SO3_DIM + i] = a * rsqrtf(300.0f * (float)(2 * l + 1));
}

// ================= fallback fp32 path kernels (round-1, verified) =================
__global__ __launch_bounds__(THREADS) void k_gemm_nt_relu(
    const float* __restrict__ A, const float* __restrict__ Bm, float* __restrict__ Cm,
    int M, int N, int K) {
  __shared__ float As[16][68];
  __shared__ float Bs[16][68];
  const int bm = blockIdx.y * 64, bn = blockIdx.x * 64;
  const int t  = threadIdx.x;
  const int lk = t & 15, lm = t >> 4;
  const int tn = t & 15, tm = t >> 4;
  float acc[4][4] = {};
  for (int k0 = 0; k0 < K; k0 += 16) {
    int gk = k0 + lk;
#pragma unroll
    for (int j = 0; j < 4; ++j) {
      int m  = lm + 16 * j;
      int gm = bm + m;
      As[lk][m] = (gm < M && gk < K) ? A[(size_t)gm * K + gk] : 0.f;
      int gn = bn + m;
      Bs[lk][m] = (gn < N && gk < K) ? Bm[(size_t)gn * K + gk] : 0.f;
    }
    __syncthreads();
#pragma unroll
    for (int k = 0; k < 16; ++k) {
      float4 av = *(const float4*)&As[k][tm * 4];
      float4 bv = *(const float4*)&Bs[k][tn * 4];
      float a[4] = {av.x, av.y, av.z, av.w};
      float bb[4] = {bv.x, bv.y, bv.z, bv.w};
#pragma unroll
      for (int i2 = 0; i2 < 4; ++i2)
#pragma unroll
        for (int j2 = 0; j2 < 4; ++j2)
          acc[i2][j2] += a[i2] * bb[j2];
    }
    __syncthreads();
  }
#pragma unroll
  for (int i2 = 0; i2 < 4; ++i2) {
    int gm = bm + tm * 4 + i2;
    if (gm >= M) continue;
#pragma unroll
    for (int j2 = 0; j2 < 4; ++j2) {
      int gn = bn + tn * 4 + j2;
      if (gn < N) Cm[(size_t)gm * N + gn] = fmaxf(acc[i2][j2], 0.f);
    }
  }
}

__global__ __launch_bounds__(THREADS) void k_gemm_nn(
    const float* __restrict__ A, const float* __restrict__ Bm, float* __restrict__ Cm,
    int M, int N, int K, int kSpan, float scale, size_t cStride) {
  __shared__ float As[16][68];
  __shared__ float Bs[16][68];
  const int bm = blockIdx.y * 64, bn = blockIdx.x * 64;
  const int t   = threadIdx.x;
  const int lk  = t & 15, lm = t >> 4;
  const int ln  = t & 63, lkq = t >> 6;
  const int tn  = t & 15, tm = t >> 4;
  const int kBegin = blockIdx.z * kSpan;
  const int kEnd   = kBegin + kSpan;
  float* C = Cm + (size_t)blockIdx.z * cStride;
  float acc[4][4] = {};
  for (int k0 = kBegin; k0 < kEnd; k0 += 16) {
    {
      int gk = k0 + lk;
#pragma unroll
      for (int j = 0; j < 4; ++j) {
        int m = lm + 16 * j, gm = bm + m;
        As[lk][m] = (gm < M) ? A[(size_t)gm * K + gk] : 0.f;
      }
    }
    {
      int gn = bn + ln;
#pragma unroll
      for (int j = 0; j < 4; ++j) {
        int k = lkq + 4 * j;
        Bs[k][ln] = (gn < N) ? Bm[(size_t)(k0 + k) * N + gn] : 0.f;
      }
    }
    __syncthreads();
#pragma unroll
    for (int k = 0; k < 16; ++k) {
      float4 av = *(const float4*)&As[k][tm * 4];
      float4 bv = *(const float4*)&Bs[k][tn * 4];
      float a[4] = {av.x, av.y, av.z, av.w};
      float bb[4] = {bv.x, bv.y, bv.z, bv.w};
#pragma unroll
      for (int i2 = 0; i2 < 4; ++i2)
#pragma unroll
        for (int j2 = 0; j2 < 4; ++j2)
          acc[i2][j2] += a[i2] * bb[j2];
    }
    __syncthreads();
  }
#pragma unroll
  for (int i2 = 0; i2 < 4; ++i2) {
    int gm = bm + tm * 4 + i2;
    if (gm >= M) continue;
#pragma unroll
    for (int j2 = 0; j2 < 4; ++j2) {
      int gn = bn + tn * 4 + j2;
      if (gn < N) C[(size_t)gm * N + gn] = acc[i2][j2] * scale;
    }
  }
}

__global__ __launch_bounds__(THREADS) void k_reduce_psi2(
    const float* __restrict__ parts, float* __restrict__ psi2) {
  int idx = blockIdx.x * THREADS + threadIdx.x;
  if (idx >= F_SO3 * SO3_DIM) return;
  float acc = 0.f;
#pragma unroll
  for (int s = 0; s < 8; ++s) acc += parts[(size_t)s * (F_SO3 * SO3_DIM) + idx];
  psi2[idx] = acc * (1.0f / 192.0f);
}

__global__ __launch_bounds__(THREADS) void k_stage_f(
    const float* __restrict__ z2, const float* __restrict__ psi2, float* __restrict__ out,
    int zStride) {
  const int b = blockIdx.x / 9;
  const int l = blockIdx.x % 9;
  const int d = 2 * l + 1, d2 = d * d;
  const int off = d_SO3_OFF[l];
  __shared__ float zb[10][289];
  __shared__ float pb[10][289];
  const int tid = threadIdx.x;
  float acc[2] = {0.f, 0.f};
  const float scale = rsqrtf(300.0f * (float)d);
  for (int fc = 0; fc < F_SO3; fc += 10) {
    for (int t = tid; t < 10 * d2; t += THREADS) {
      int fl = t / d2, q = t - fl * d2;
      int f  = fc + fl;
      zb[fl][q] = z2[((size_t)b * F_SO3 + f) * zStride + off + q];
      pb[fl][q] = psi2[(size_t)f * SO3_DIM + off + q];
    }
    __syncthreads();
#pragma unroll 2
    for (int io = 0; io < 2; ++io) {
      int i = tid + io * THREADS;
      if (i < d2) {
        int v = i / d, m = i - v * d;
        float a = acc[io];
#pragma unroll
        for (int fl = 0; fl < 10; ++fl) {
          float s_ = 0.f;
          for (int u = 0; u < d; ++u)
            s_ += zb[fl][u * d + m] * pb[fl][v * d + u];
          a += s_;
        }
        acc[io] = a;
      }
    }
    __syncthreads();
  }
  for (int io = 0; io < 2; ++io) {
    int i = tid + io * THREADS;
    if (i < d2) out[(size_t)b * SO3_DIM + off + i] = acc[io] * scale;
  }
}

// ================= launch =================
extern "C" void kernel_launch(void* const* d_in, const int* in_sizes, int n_in,
                              void* d_out, int out_size, void* d_ws, size_t ws_size,
                              hipStream_t stream) {
  const float* x     = (const float*)d_in[0];
  const float* Fm    = (const float*)d_in[1];
  const float* w_s2  = (const float*)d_in[2];
  const float* Y     = (const float*)d_in[3];
  const float* w_so3 = (const float*)d_in[4];
  const float* D     = (const float*)d_in[5];
  const float* D_act = (const float*)d_in[6];
  float* out = (float*)d_out;

  if (ws_size >= FAST_NEED) {
    char* p = (char*)d_ws;
    float*          y       = (float*)(p + O_Y);
    float*          psi     = (float*)(p + O_PSI);
    __hip_bfloat16* z_bf    = (__hip_bfloat16*)(p + O_ZBF);
    __hip_bfloat16* Dact_bf = (__hip_bfloat16*)(p + O_DACT);
    __hip_bfloat16* DactT_bf= (__hip_bfloat16*)(p + O_DACTT);
    __hip_bfloat16* wso3_bf = (__hip_bfloat16*)(p + O_WSO3);
    __hip_bfloat16* DT_bf   = (__hip_bfloat16*)(p + O_DT);
    __hip_bfloat16* s_bf    = (__hip_bfloat16*)(p + O_SBF);
    float*          d2p     = (float*)(p + O_D2P);
    float*          z2p     = (float*)(p + O_Z2P);
    float*          e1p     = (float*)(p + O_E1P);
    float*          psi2    = (float*)(p + O_PSI2);
    float*          sfp     = (float*)(p + O_SFP);

    // operand conversions
    k_cvt_pad<<<(4096 * 1024 + THREADS - 1) / THREADS, THREADS, 0, stream>>>(
        D_act, Dact_bf, G_ACT, SO3_DIM, 1024, 4096);
    k_transpose_cvt<<<dim3(31, 128), THREADS, 0, stream>>>(D_act, DactT_bf, G_ACT, SO3_DIM, 4096);
    k_cvt_pad<<<(384 * 36864 + THREADS - 1) / THREADS, THREADS, 0, stream>>>(
        w_so3, wso3_bf, F_SO3, G_SO3, G_SO3, 384);
    k_transpose_cvt<<<dim3(31, 1152), THREADS, 0, stream>>>(D, DT_bf, G_SO3, SO3_DIM, 36864);

    // A, B, C stages
    k_stage_a3<<<NPAIR / 3, THREADS, 0, stream>>>(Fm, x, y);
    k_psi<<<(F_IN * F_SO3 * S2_DIM + THREADS - 1) / THREADS, THREADS, 0, stream>>>(w_s2, Y, psi);
    k_stage_c_bf<<<B_ * F_SO3, THREADS, 0, stream>>>(y, psi, z_bf);

    // D1: s = relu(z @ D_act^T), bf16 out. M=2432 N=4096 K=1024
    k_mfma_nt<1><<<dim3(32, 19, 1), THREADS, 0, stream>>>(
        z_bf, Dact_bf, s_bf, 1024, 1024, 4096, 1.f, 0);
    // D2: z2 = s @ D_act / 4096. M=2432 N=1024 K=4096, split-K 4
    k_mfma_nt<0><<<dim3(8, 19, D2_SPLIT), THREADS, 0, stream>>>(
        s_bf, DactT_bf, d2p, 4096, 4096 / D2_SPLIT, 1024, 1.f, (size_t)2432 * 1024);
    k_reduce_split<<<(2400 * 969 + THREADS - 1) / THREADS, THREADS, 0, stream>>>(
        d2p, z2p, 2400, 969, 1024, (size_t)2432 * 1024, 1024, D2_SPLIT, 1.0f / G_ACT);
    // E1: psi2 = w_so3 @ D / 192. M=384 N=1024 K=36864, split-K 32
    k_mfma_nt<0><<<dim3(8, 3, E1_SPLIT), THREADS, 0, stream>>>(
        wso3_bf, DT_bf, e1p, G_SO3, G_SO3 / E1_SPLIT, 1024, 1.f, (size_t)384 * 1024);
    k_reduce_split<<<(300 * 969 + THREADS - 1) / THREADS, THREADS, 0, stream>>>(
        e1p, psi2, 300, 969, 1024, (size_t)384 * 1024, 969, E1_SPLIT, 1.0f / 192.0f);

    // F: final per-l contraction, split over f
    k_stage_f_part<<<dim3(B_ * 9, F_SPLIT), THREADS, 0, stream>>>(z2p, psi2, sfp, 1024);
    k_stage_f_red<<<(8 * SO3_DIM + THREADS - 1) / THREADS, THREADS, 0, stream>>>(sfp, out);
  } else {
    float* ws  = (float*)d_ws;
    float* y    = ws + WS_Y;
    float* psi  = ws + WS_PSI;
    float* z    = ws + WS_Z;
    float* s    = ws + WS_S;
    float* z2   = ws + WS_Z2;
    float* p2p  = ws + WS_P2P;
    float* psi2 = ws + WS_PSI2;

    k_stage_a3<<<NPAIR / 3, THREADS, 0, stream>>>(Fm, x, y);
    k_psi<<<(F_IN * F_SO3 * S2_DIM + THREADS - 1) / THREADS, THREADS, 0, stream>>>(w_s2, Y, psi);
    k_stage_c<<<B_ * F_SO3, THREADS, 0, stream>>>(y, psi, z);
    k_gemm_nt_relu<<<dim3(G_ACT / 64, (B_ * F_SO3 + 63) / 64), THREADS, 0, stream>>>(
        z, D_act, s, B_ * F_SO3, G_ACT, SO3_DIM);
    k_gemm_nn<<<dim3((SO3_DIM + 63) / 64, (B_ * F_SO3 + 63) / 64, 1), THREADS, 0, stream>>>(
        s, D_act, z2, B_ * F_SO3, SO3_DIM, G_ACT, G_ACT, 1.0f / G_ACT, 0);
    k_gemm_nn<<<dim3((SO3_DIM + 63) / 64, (F_SO3 + 63) / 64, 8), THREADS, 0, stream>>>(
        w_so3, D, p2p, F_SO3, SO3_DIM, G_SO3, G_SO3 / 8, 1.0f, (size_t)F_SO3 * SO3_DIM);
    k_reduce_psi2<<<(F_SO3 * SO3_DIM + THREADS - 1) / THREADS, THREADS, 0, stream>>>(p2p, psi2);
    k_stage_f<<<B_ * 9, THREADS, 0, stream>>>(z2, psi2, out, SO3_DIM);
  }
}

// Round 4
// 611.006 us; speedup vs baseline: 3.6072x; 1.0521x over previous
//
#include <hip/hip_runtime.h>
#include <hip/hip_bf16.h>
#include <math.h>

#define THREADS 256

// ---------------- problem constants ----------------
constexpr int B_    = 8;
constexpr int C_    = 768;
constexpr int KS_   = 7;
constexpr int F_IN  = 81;
constexpr int F_SO3 = 300;
constexpr int S2_DIM  = 81;
constexpr int SO3_DIM = 969;
constexpr int G_S2  = 48;
constexpr int G_ACT = 4096;
constexpr int G_SO3 = 36864;
constexpr int CKK   = C_ * KS_ * KS_;   // 37632
constexpr int CKK4  = CKK / 4;          // 9408
constexpr int NPAIR = F_IN * S2_DIM;    // 6561

constexpr int D2_SPLIT = 4;
constexpr int E1_SPLIT = 16;
constexpr int F_SPLIT  = 5;   // 300 / 60

__constant__ int d_S2_OFF[10]  = {0, 1, 4, 9, 16, 25, 36, 49, 64, 81};
__constant__ int d_SO3_OFF[10] = {0, 1, 10, 35, 84, 165, 286, 455, 680, 969};

// i -> (u, m, so, l) lookup for the SO3 index space
struct CEnt { unsigned char u, m, so, l; };
struct CLut { CEnt v[992]; };
constexpr CLut make_clut() {
  CLut t{};
  int S2O[10]  = {0, 1, 4, 9, 16, 25, 36, 49, 64, 81};
  int SO3O[10] = {0, 1, 10, 35, 84, 165, 286, 455, 680, 969};
  for (int i = 0; i < 969; ++i) {
    int l = 0;
    while (i >= SO3O[l + 1]) ++l;
    int d = 2 * l + 1, r = i - SO3O[l];
    t.v[i].u  = (unsigned char)(r / d);
    t.v[i].m  = (unsigned char)(r % d);
    t.v[i].so = (unsigned char)S2O[l];
    t.v[i].l  = (unsigned char)l;
  }
  return t;
}
__constant__ CLut g_clut = make_clut();

using short8 = __attribute__((ext_vector_type(8))) short;
using f32x4  = __attribute__((ext_vector_type(4))) float;
using f4v    = __attribute__((ext_vector_type(4))) float;

#define GL16(gp, lp)                                                        \
  __builtin_amdgcn_global_load_lds(                                         \
      (const __attribute__((address_space(1))) void*)(gp),                  \
      (__attribute__((address_space(3))) void*)(lp), 16, 0, 0)

// ---------------- FAST-PATH workspace layout (bytes) ----------------
constexpr size_t AL(size_t x) { return (x + 1023) & ~(size_t)1023; }
constexpr size_t O_Y     = 0;
constexpr size_t O_PSI   = O_Y     + AL((size_t)8 * NPAIR * 4);
constexpr size_t O_ZBF   = O_PSI   + AL((size_t)F_IN * F_SO3 * 81 * 4);
constexpr size_t O_DACT  = O_ZBF   + AL((size_t)2432 * 1024 * 2);
constexpr size_t O_DACTT = O_DACT  + AL((size_t)4096 * 1024 * 2);
constexpr size_t O_WSO3  = O_DACTT + AL((size_t)1024 * 4096 * 2);
constexpr size_t O_DT    = O_WSO3  + AL((size_t)384 * 36864 * 2);
constexpr size_t O_SBF   = O_DT    + AL((size_t)1024 * 36864 * 2);
constexpr size_t O_D2P   = O_SBF   + AL((size_t)2432 * 4096 * 2);
constexpr size_t O_E1P   = O_D2P   + AL((size_t)D2_SPLIT * 2432 * 1024 * 4);
constexpr size_t O_PSI2  = O_E1P   + AL((size_t)E1_SPLIT * 384 * 1024 * 4);
constexpr size_t O_SFP   = O_PSI2  + AL((size_t)F_SO3 * SO3_DIM * 4);
constexpr size_t FAST_NEED = O_SFP + AL((size_t)F_SPLIT * 8 * SO3_DIM * 4);

// ---------------- FALLBACK workspace layout (floats, round-1) ----------------
constexpr size_t WS_Y    = 0;
constexpr size_t WS_PSI  = 52488;
constexpr size_t WS_Z    = 2020788;
constexpr size_t WS_S    = 4346388;
constexpr size_t WS_Z2   = 14176788;
constexpr size_t WS_P2P  = 16502388;
constexpr size_t WS_PSI2 = 18827988;

// ================= stage A: y[b,f,s] = dot(F[f,s,:], x[b,:]) =================
__global__ __launch_bounds__(THREADS) void k_stage_a3(
    const float* __restrict__ Fm, const float* __restrict__ x, float* __restrict__ y) {
  const int p0  = blockIdx.x * 3;
  const int tid = threadIdx.x;
  const f4v* __restrict__ F4 = (const f4v*)Fm;
  const f4v* __restrict__ x4 = (const f4v*)x;

  float acc[3][8];
#pragma unroll
  for (int p = 0; p < 3; ++p)
#pragma unroll
    for (int b = 0; b < 8; ++b) acc[p][b] = 0.f;

  for (int i = tid; i < CKK4; i += THREADS) {
    f4v xv[8];
#pragma unroll
    for (int b = 0; b < 8; ++b) xv[b] = x4[b * CKK4 + i];
#pragma unroll
    for (int p = 0; p < 3; ++p) {
      f4v fv = __builtin_nontemporal_load(&F4[(size_t)(p0 + p) * CKK4 + i]);
#pragma unroll
      for (int b = 0; b < 8; ++b)
        acc[p][b] += fv[0] * xv[b][0] + fv[1] * xv[b][1] + fv[2] * xv[b][2] + fv[3] * xv[b][3];
    }
  }

  __shared__ float red[4][24];
  const int lane = tid & 63, wid = tid >> 6;
#pragma unroll
  for (int p = 0; p < 3; ++p) {
#pragma unroll
    for (int b = 0; b < 8; ++b) {
      float v = acc[p][b];
      v += __shfl_down(v, 32);
      v += __shfl_down(v, 16);
      v += __shfl_down(v, 8);
      v += __shfl_down(v, 4);
      v += __shfl_down(v, 2);
      v += __shfl_down(v, 1);
      if (lane == 0) red[wid][p * 8 + b] = v;
    }
  }
  __syncthreads();
  if (tid < 24) {
    float v = red[0][tid] + red[1][tid] + red[2][tid] + red[3][tid];
    int p = tid / 8, b = tid % 8;
    y[(size_t)b * NPAIR + p0 + p] = v;
  }
}

// ================= über segment bodies =================
__device__ __forceinline__ void cvt_body(const float* __restrict__ src,
                                         __hip_bfloat16* __restrict__ dst,
                                         int R, int Cs, int Cp, int blk) {
  size_t idx = (size_t)blk * THREADS + threadIdx.x;
  int r = (int)(idx / (unsigned)Cp), c = (int)(idx % (unsigned)Cp);
  float v = (r < R && c < Cs) ? src[(size_t)r * Cs + c] : 0.f;
  dst[idx] = __float2bfloat16(v);
}

__device__ __forceinline__ void tr_body(const float* __restrict__ src,
                                        __hip_bfloat16* __restrict__ dst,
                                        int R, int Cs, size_t dstStride, int bx, int by) {
  __shared__ float tile[32][33];
  const int c0 = bx * 32, r0 = by * 32;
  const int tx = threadIdx.x & 31, ty = threadIdx.x >> 5;  // 32 x 8
#pragma unroll
  for (int i = 0; i < 32; i += 8) {
    int r = r0 + ty + i, c = c0 + tx;
    tile[ty + i][tx] = (r < R && c < Cs) ? src[(size_t)r * Cs + c] : 0.f;
  }
  __syncthreads();
#pragma unroll
  for (int i = 0; i < 32; i += 8) {
    int c = c0 + ty + i, r = r0 + tx;
    if (c < Cs && r < R) dst[(size_t)c * dstStride + r] = __float2bfloat16(tile[tx][ty + i]);
  }
}

__device__ __forceinline__ void psi_body(const float* __restrict__ w_s2,
                                         const float* __restrict__ Y,
                                         float* __restrict__ psi, int blk) {
  int idx = blk * THREADS + threadIdx.x;
  if (idx >= F_IN * F_SO3 * S2_DIM) return;
  int s  = idx % S2_DIM;
  int fg = idx / S2_DIM;
  const float* w = w_s2 + (size_t)fg * G_S2;
  float acc = 0.f;
#pragma unroll 8
  for (int n = 0; n < G_S2; ++n) acc += w[n] * Y[n * S2_DIM + s];
  psi[idx] = acc * 0.14433756729740643f;
}

// segments: cvt(D_act) | T(D_act) | cvt(w_so3) | T(D) | psi
constexpr int UB1 = 16384;
constexpr int UB2 = 3968;    // 31 x 128
constexpr int UB3 = 55296;
constexpr int UB4 = 35712;   // 31 x 1152
constexpr int UB5 = 7689;
constexpr int UB_TOT = UB1 + UB2 + UB3 + UB4 + UB5;

__global__ __launch_bounds__(THREADS) void k_uber(
    const float* __restrict__ D_act, __hip_bfloat16* __restrict__ Dact_bf,
    __hip_bfloat16* __restrict__ DactT_bf,
    const float* __restrict__ w_so3, __hip_bfloat16* __restrict__ wso3_bf,
    const float* __restrict__ D, __hip_bfloat16* __restrict__ DT_bf,
    const float* __restrict__ w_s2, const float* __restrict__ Y, float* __restrict__ psi) {
  int b = blockIdx.x;
  if (b < UB1) { cvt_body(D_act, Dact_bf, G_ACT, SO3_DIM, 1024, b); return; }
  b -= UB1;
  if (b < UB2) { tr_body(D_act, DactT_bf, G_ACT, SO3_DIM, 4096, b % 31, b / 31); return; }
  b -= UB2;
  if (b < UB3) { cvt_body(w_so3, wso3_bf, F_SO3, G_SO3, G_SO3, b); return; }
  b -= UB3;
  if (b < UB4) { tr_body(D, DT_bf, G_SO3, SO3_DIM, 36864, b % 31, b / 31); return; }
  b -= UB4;
  psi_body(w_s2, Y, psi, b);
}

// ================= stage C (bf16 out, padded stride 1024) =================
__global__ __launch_bounds__(THREADS) void k_stage_c_bf(
    const float* __restrict__ y, const float* __restrict__ psi, __hip_bfloat16* __restrict__ z) {
  const int b = blockIdx.x / F_SO3;
  const int g = blockIdx.x % F_SO3;
  __shared__ float ybl[NPAIR];
  __shared__ float psl[NPAIR];
  const int tid = threadIdx.x;
  for (int t = tid; t < NPAIR; t += THREADS) {
    ybl[t] = y[(size_t)b * NPAIR + t];
    int f = t / S2_DIM, s = t % S2_DIM;
    psl[t] = psi[((size_t)f * F_SO3 + g) * S2_DIM + s];
  }
  __syncthreads();
  for (int i = tid; i < 1024; i += THREADS) {
    float acc = 0.f;
    if (i < SO3_DIM) {
      CEnt e = g_clut.v[i];
      int im = e.so + e.m, iu = e.so + e.u;
#pragma unroll 9
      for (int f = 0; f < F_IN; ++f)
        acc += ybl[f * S2_DIM + im] * psl[f * S2_DIM + iu];
      acc *= (1.0f / 9.0f);
    }
    z[((size_t)b * F_SO3 + g) * 1024 + i] = __float2bfloat16(acc);
  }
}

// ================= bf16 MFMA GEMM body, NT: C = scale*(A @ B^T) =================
struct GemmDesc {
  const __hip_bfloat16* A;
  const __hip_bfloat16* B;
  void* C;
  int K, kSpan, Ncols;
  float scale;
  size_t splitStride;
  int gx, gy, gz, epi;   // epi 0: fp32 out (+split offset); 1: bf16 relu out
};

__device__ __forceinline__ void mfma_nt_body(const GemmDesc g, unsigned lin) {
  __shared__ __align__(16) char smem[32768];
  char* As = smem;
  char* Bs = smem + 16384;

  unsigned nwg = (unsigned)(g.gx * g.gy * g.gz);
  if ((nwg & 7u) == 0u) {
    unsigned q = nwg >> 3;
    lin = (lin & 7u) * q + (lin >> 3);
  }
  const int bxi = (int)(lin % (unsigned)g.gx);
  const unsigned t1 = lin / (unsigned)g.gx;
  const int byi = (int)(t1 % (unsigned)g.gy);
  const int bzi = (int)(t1 / (unsigned)g.gy);

  const int t    = threadIdx.x;
  const int lane = t & 63;
  const int wave = t >> 6;
  const int wr   = wave >> 1, wc = wave & 1;
  const int bm = byi * 128, bn = bxi * 128;
  const int kBegin = bzi * g.kSpan;
  const int kEnd   = kBegin + g.kSpan;

  const char* pA[4];
  const char* pB[4];
  int ldsOff[4];
#pragma unroll
  for (int i = 0; i < 4; ++i) {
    int L   = i * 4096 + t * 16;
    int row = L >> 7;                        // 128 B per row (64 bf16)
    int kb  = (L & 127) ^ ((row & 7) << 4);  // inverse-swizzled source column
    pA[i] = (const char*)g.A + ((size_t)(bm + row) * g.K) * 2 + kb;
    pB[i] = (const char*)g.B + ((size_t)(bn + row) * g.K) * 2 + kb;
    ldsOff[i] = L;
  }

  f32x4 acc[4][4] = {};

  for (int k0 = kBegin; k0 < kEnd; k0 += 64) {
    size_t koff = (size_t)k0 * 2;
#pragma unroll
    for (int i = 0; i < 4; ++i) {
      GL16(pA[i] + koff, As + ldsOff[i]);
      GL16(pB[i] + koff, Bs + ldsOff[i]);
    }
    __syncthreads();
#pragma unroll
    for (int kk = 0; kk < 2; ++kk) {
      const int klin = kk * 64 + ((lane >> 4) << 4);
      short8 af[4], bfr[4];
#pragma unroll
      for (int m = 0; m < 4; ++m) {
        int ra = (wr << 6) + (m << 4) + (lane & 15);
        af[m] = *(const short8*)(As + ra * 128 + (klin ^ ((ra & 7) << 4)));
        int rb = (wc << 6) + (m << 4) + (lane & 15);
        bfr[m] = *(const short8*)(Bs + rb * 128 + (klin ^ ((rb & 7) << 4)));
      }
#pragma unroll
      for (int m = 0; m < 4; ++m)
#pragma unroll
        for (int n = 0; n < 4; ++n)
          acc[m][n] = __builtin_amdgcn_mfma_f32_16x16x32_bf16(af[m], bfr[n], acc[m][n], 0, 0, 0);
    }
    __syncthreads();
  }

  const int rbase = bm + (wr << 6) + ((lane >> 4) << 2);
  const int cbase = bn + (wc << 6) + (lane & 15);
  if (g.epi == 0) {
    float* C = (float*)g.C + (size_t)bzi * g.splitStride;
#pragma unroll
    for (int m = 0; m < 4; ++m)
#pragma unroll
      for (int n = 0; n < 4; ++n)
#pragma unroll
        for (int r = 0; r < 4; ++r)
          C[(size_t)(rbase + m * 16 + r) * g.Ncols + (cbase + n * 16)] = acc[m][n][r] * g.scale;
  } else {
    __hip_bfloat16* C = (__hip_bfloat16*)g.C;
#pragma unroll
    for (int m = 0; m < 4; ++m)
#pragma unroll
      for (int n = 0; n < 4; ++n)
#pragma unroll
        for (int r = 0; r < 4; ++r)
          C[(size_t)(rbase + m * 16 + r) * g.Ncols + (cbase + n * 16)] =
              __float2bfloat16(fmaxf(acc[m][n][r], 0.f));
  }
}

// two independent GEMMs in one dispatch
__global__ __launch_bounds__(THREADS) void k_mfma_dual(GemmDesc g0, GemmDesc g1, int n0) {
  if ((int)blockIdx.x < n0) mfma_nt_body(g0, blockIdx.x);
  else                      mfma_nt_body(g1, blockIdx.x - n0);
}

// one GEMM + one split-K reduce in one dispatch
__global__ __launch_bounds__(THREADS) void k_mfma_reduce(
    GemmDesc g, int n0,
    const float* __restrict__ parts, float* __restrict__ dst, int R, int C,
    size_t rowStride, size_t splitStride, size_t dstStride, int nSplit, float scale) {
  if ((int)blockIdx.x < n0) { mfma_nt_body(g, blockIdx.x); return; }
  int idx = (int)(blockIdx.x - n0) * THREADS + threadIdx.x;
  if (idx >= R * C) return;
  int r = idx / C, c = idx % C;
  float a = 0.f;
  for (int s = 0; s < nSplit; ++s) a += parts[(size_t)s * splitStride + (size_t)r * rowStride + c];
  dst[(size_t)r * dstStride + c] = a * scale;
}

// ================= stage F partials (reads D2 split partials directly) =================
__global__ __launch_bounds__(THREADS) void k_stage_f_part(
    const float* __restrict__ d2p, const float* __restrict__ psi2, float* __restrict__ partial) {
  const int b  = blockIdx.x / 9;
  const int l  = blockIdx.x % 9;
  const int sp = blockIdx.y;
  const int d = 2 * l + 1, d2 = d * d;
  const int off = d_SO3_OFF[l];
  constexpr size_t SS = (size_t)2432 * 1024;
  __shared__ float zb[10][289];
  __shared__ float pb[10][289];
  const int tid = threadIdx.x;
  float acc[2] = {0.f, 0.f};
  const int fBeg = sp * (F_SO3 / F_SPLIT), fEnd = fBeg + F_SO3 / F_SPLIT;
  for (int fc = fBeg; fc < fEnd; fc += 10) {
    for (int t = tid; t < 10 * d2; t += THREADS) {
      int fl = t / d2, q = t - fl * d2;
      int f  = fc + fl;
      size_t zi = ((size_t)b * F_SO3 + f) * 1024 + off + q;
      float zv = d2p[zi] + d2p[zi + SS] + d2p[zi + 2 * SS] + d2p[zi + 3 * SS];
      zb[fl][q] = zv * (1.0f / G_ACT);
      pb[fl][q] = psi2[(size_t)f * SO3_DIM + off + q];
    }
    __syncthreads();
#pragma unroll 2
    for (int io = 0; io < 2; ++io) {
      int i = tid + io * THREADS;
      if (i < d2) {
        int v = i / d, m = i - v * d;
        float a = acc[io];
#pragma unroll
        for (int fl = 0; fl < 10; ++fl) {
          float s_ = 0.f;
          for (int u = 0; u < d; ++u)
            s_ += zb[fl][u * d + m] * pb[fl][v * d + u];
          a += s_;
        }
        acc[io] = a;
      }
    }
    __syncthreads();
  }
  for (int io = 0; io < 2; ++io) {
    int i = tid + io * THREADS;
    if (i < d2) partial[((size_t)sp * 8 + b) * SO3_DIM + off + i] = acc[io];
  }
}

__global__ __launch_bounds__(THREADS) void k_stage_f_red(
    const float* __restrict__ partial, float* __restrict__ out) {
  int idx = blockIdx.x * THREADS + threadIdx.x;
  if (idx >= 8 * SO3_DIM) return;
  int b = idx / SO3_DIM, i = idx % SO3_DIM;
  int l = g_clut.v[i].l;
  float a = 0.f;
#pragma unroll
  for (int sp = 0; sp < F_SPLIT; ++sp)
    a += partial[((size_t)sp * 8 + b) * SO3_DIM + i];
  out[(size_t)b * SO3_DIM + i] = a * rsqrtf(300.0f * (float)(2 * l + 1));
}

// ================= fallback fp32 path kernels (round-1, verified) =================
__global__ __launch_bounds__(THREADS) void k_psi(
    const float* __restrict__ w_s2, const float* __restrict__ Y, float* __restrict__ psi) {
  psi_body(w_s2, Y, psi, blockIdx.x);
}

__global__ __launch_bounds__(THREADS) void k_stage_c(
    const float* __restrict__ y, const float* __restrict__ psi, float* __restrict__ z) {
  const int b = blockIdx.x / F_SO3;
  const int g = blockIdx.x % F_SO3;
  __shared__ float ybl[NPAIR];
  __shared__ float psl[NPAIR];
  const int tid = threadIdx.x;
  for (int t = tid; t < NPAIR; t += THREADS) {
    ybl[t] = y[(size_t)b * NPAIR + t];
    int f = t / S2_DIM, s = t % S2_DIM;
    psl[t] = psi[((size_t)f * F_SO3 + g) * S2_DIM + s];
  }
  __syncthreads();
  for (int i = tid; i < SO3_DIM; i += THREADS) {
    CEnt e = g_clut.v[i];
    int im = e.so + e.m, iu = e.so + e.u;
    float acc = 0.f;
#pragma unroll 9
    for (int f = 0; f < F_IN; ++f)
      acc += ybl[f * S2_DIM + im] * psl[f * S2_DIM + iu];
    z[((size_t)b * F_SO3 + g) * SO3_DIM + i] = acc * (1.0f / 9.0f);
  }
}

__global__ __launch_bounds__(THREADS) void k_gemm_nt_relu(
    const float* __restrict__ A, const float* __restrict__ Bm, float* __restrict__ Cm,
    int M, int N, int K) {
  __shared__ float As[16][68];
  __shared__ float Bs[16][68];
  const int bm = blockIdx.y * 64, bn = blockIdx.x * 64;
  const int t  = threadIdx.x;
  const int lk = t & 15, lm = t >> 4;
  const int tn = t & 15, tm = t >> 4;
  float acc[4][4] = {};
  for (int k0 = 0; k0 < K; k0 += 16) {
    int gk = k0 + lk;
#pragma unroll
    for (int j = 0; j < 4; ++j) {
      int m  = lm + 16 * j;
      int gm = bm + m;
      As[lk][m] = (gm < M && gk < K) ? A[(size_t)gm * K + gk] : 0.f;
      int gn = bn + m;
      Bs[lk][m] = (gn < N && gk < K) ? Bm[(size_t)gn * K + gk] : 0.f;
    }
    __syncthreads();
#pragma unroll
    for (int k = 0; k < 16; ++k) {
      float4 av = *(const float4*)&As[k][tm * 4];
      float4 bv = *(const float4*)&Bs[k][tn * 4];
      float a[4] = {av.x, av.y, av.z, av.w};
      float bb[4] = {bv.x, bv.y, bv.z, bv.w};
#pragma unroll
      for (int i2 = 0; i2 < 4; ++i2)
#pragma unroll
        for (int j2 = 0; j2 < 4; ++j2)
          acc[i2][j2] += a[i2] * bb[j2];
    }
    __syncthreads();
  }
#pragma unroll
  for (int i2 = 0; i2 < 4; ++i2) {
    int gm = bm + tm * 4 + i2;
    if (gm >= M) continue;
#pragma unroll
    for (int j2 = 0; j2 < 4; ++j2) {
      int gn = bn + tn * 4 + j2;
      if (gn < N) Cm[(size_t)gm * N + gn] = fmaxf(acc[i2][j2], 0.f);
    }
  }
}

__global__ __launch_bounds__(THREADS) void k_gemm_nn(
    const float* __restrict__ A, const float* __restrict__ Bm, float* __restrict__ Cm,
    int M, int N, int K, int kSpan, float scale, size_t cStride) {
  __shared__ float As[16][68];
  __shared__ float Bs[16][68];
  const int bm = blockIdx.y * 64, bn = blockIdx.x * 64;
  const int t   = threadIdx.x;
  const int lk  = t & 15, lm = t >> 4;
  const int ln  = t & 63, lkq = t >> 6;
  const int tn  = t & 15, tm = t >> 4;
  const int kBegin = blockIdx.z * kSpan;
  const int kEnd   = kBegin + kSpan;
  float* C = Cm + (size_t)blockIdx.z * cStride;
  float acc[4][4] = {};
  for (int k0 = kBegin; k0 < kEnd; k0 += 16) {
    {
      int gk = k0 + lk;
#pragma unroll
      for (int j = 0; j < 4; ++j) {
        int m = lm + 16 * j, gm = bm + m;
        As[lk][m] = (gm < M) ? A[(size_t)gm * K + gk] : 0.f;
      }
    }
    {
      int gn = bn + ln;
#pragma unroll
      for (int j = 0; j < 4; ++j) {
        int k = lkq + 4 * j;
        Bs[k][ln] = (gn < N) ? Bm[(size_t)(k0 + k) * N + gn] : 0.f;
      }
    }
    __syncthreads();
#pragma unroll
    for (int k = 0; k < 16; ++k) {
      float4 av = *(const float4*)&As[k][tm * 4];
      float4 bv = *(const float4*)&Bs[k][tn * 4];
      float a[4] = {av.x, av.y, av.z, av.w};
      float bb[4] = {bv.x, bv.y, bv.z, bv.w};
#pragma unroll
      for (int i2 = 0; i2 < 4; ++i2)
#pragma unroll
        for (int j2 = 0; j2 < 4; ++j2)
          acc[i2][j2] += a[i2] * bb[j2];
    }
    __syncthreads();
  }
#pragma unroll
  for (int i2 = 0; i2 < 4; ++i2) {
    int gm = bm + tm * 4 + i2;
    if (gm >= M) continue;
#pragma unroll
    for (int j2 = 0; j2 < 4; ++j2) {
      int gn = bn + tn * 4 + j2;
      if (gn < N) C[(size_t)gm * N + gn] = acc[i2][j2] * scale;
    }
  }
}

__global__ __launch_bounds__(THREADS) void k_reduce_psi2(
    const float* __restrict__ parts, float* __restrict__ psi2) {
  int idx = blockIdx.x * THREADS + threadIdx.x;
  if (idx >= F_SO3 * SO3_DIM) return;
  float acc = 0.f;
#pragma unroll
  for (int s = 0; s < 8; ++s) acc += parts[(size_t)s * (F_SO3 * SO3_DIM) + idx];
  psi2[idx] = acc * (1.0f / 192.0f);
}

__global__ __launch_bounds__(THREADS) void k_stage_f(
    const float* __restrict__ z2, const float* __restrict__ psi2, float* __restrict__ out,
    int zStride) {
  const int b = blockIdx.x / 9;
  const int l = blockIdx.x % 9;
  const int d = 2 * l + 1, d2 = d * d;
  const int off = d_SO3_OFF[l];
  __shared__ float zb[10][289];
  __shared__ float pb[10][289];
  const int tid = threadIdx.x;
  float acc[2] = {0.f, 0.f};
  const float scale = rsqrtf(300.0f * (float)d);
  for (int fc = 0; fc < F_SO3; fc += 10) {
    for (int t = tid; t < 10 * d2; t += THREADS) {
      int fl = t / d2, q = t - fl * d2;
      int f  = fc + fl;
      zb[fl][q] = z2[((size_t)b * F_SO3 + f) * zStride + off + q];
      pb[fl][q] = psi2[(size_t)f * SO3_DIM + off + q];
    }
    __syncthreads();
#pragma unroll 2
    for (int io = 0; io < 2; ++io) {
      int i = tid + io * THREADS;
      if (i < d2) {
        int v = i / d, m = i - v * d;
        float a = acc[io];
#pragma unroll
        for (int fl = 0; fl < 10; ++fl) {
          float s_ = 0.f;
          for (int u = 0; u < d; ++u)
            s_ += zb[fl][u * d + m] * pb[fl][v * d + u];
          a += s_;
        }
        acc[io] = a;
      }
    }
    __syncthreads();
  }
  for (int io = 0; io < 2; ++io) {
    int i = tid + io * THREADS;
    if (i < d2) out[(size_t)b * SO3_DIM + off + i] = acc[io] * scale;
  }
}

// ================= launch =================
extern "C" void kernel_launch(void* const* d_in, const int* in_sizes, int n_in,
                              void* d_out, int out_size, void* d_ws, size_t ws_size,
                              hipStream_t stream) {
  const float* x     = (const float*)d_in[0];
  const float* Fm    = (const float*)d_in[1];
  const float* w_s2  = (const float*)d_in[2];
  const float* Y     = (const float*)d_in[3];
  const float* w_so3 = (const float*)d_in[4];
  const float* D     = (const float*)d_in[5];
  const float* D_act = (const float*)d_in[6];
  float* out = (float*)d_out;

  if (ws_size >= FAST_NEED) {
    char* p = (char*)d_ws;
    float*          y       = (float*)(p + O_Y);
    float*          psi     = (float*)(p + O_PSI);
    __hip_bfloat16* z_bf    = (__hip_bfloat16*)(p + O_ZBF);
    __hip_bfloat16* Dact_bf = (__hip_bfloat16*)(p + O_DACT);
    __hip_bfloat16* DactT_bf= (__hip_bfloat16*)(p + O_DACTT);
    __hip_bfloat16* wso3_bf = (__hip_bfloat16*)(p + O_WSO3);
    __hip_bfloat16* DT_bf   = (__hip_bfloat16*)(p + O_DT);
    __hip_bfloat16* s_bf    = (__hip_bfloat16*)(p + O_SBF);
    float*          d2p     = (float*)(p + O_D2P);
    float*          e1p     = (float*)(p + O_E1P);
    float*          psi2    = (float*)(p + O_PSI2);
    float*          sfp     = (float*)(p + O_SFP);

    // 1) stage A (memory-bound floor: 987 MB of F)
    k_stage_a3<<<NPAIR / 3, THREADS, 0, stream>>>(Fm, x, y);
    // 2) fused conversions + psi
    k_uber<<<UB_TOT, THREADS, 0, stream>>>(
        D_act, Dact_bf, DactT_bf, w_so3, wso3_bf, D, DT_bf, w_s2, Y, psi);
    // 3) stage C -> z bf16
    k_stage_c_bf<<<B_ * F_SO3, THREADS, 0, stream>>>(y, psi, z_bf);

    // 4) dual: E1 (psi2 partials) + D1 (s = relu(z@Dact^T))
    GemmDesc e1{wso3_bf, DT_bf, e1p, G_SO3, G_SO3 / E1_SPLIT, 1024, 1.f,
                (size_t)384 * 1024, 8, 3, E1_SPLIT, 0};
    GemmDesc d1{z_bf, Dact_bf, s_bf, 1024, 1024, 4096, 1.f, 0, 32, 19, 1, 1};
    int nE1 = 8 * 3 * E1_SPLIT;          // 384
    int nD1 = 32 * 19;                   // 608
    k_mfma_dual<<<nE1 + nD1, THREADS, 0, stream>>>(e1, d1, nE1);

    // 5) dual: D2 (z2 partials) + E1 reduce -> psi2
    GemmDesc d2{s_bf, DactT_bf, d2p, 4096, 4096 / D2_SPLIT, 1024, 1.f,
                (size_t)2432 * 1024, 8, 19, D2_SPLIT, 0};
    int nD2 = 8 * 19 * D2_SPLIT;         // 608
    int nE1r = (F_SO3 * SO3_DIM + THREADS - 1) / THREADS;  // 1136
    k_mfma_reduce<<<nD2 + nE1r, THREADS, 0, stream>>>(
        d2, nD2, e1p, psi2, F_SO3, SO3_DIM, 1024, (size_t)384 * 1024, SO3_DIM,
        E1_SPLIT, 1.0f / 192.0f);

    // 6) stage F partials (folds the D2 split-reduce + /4096)
    k_stage_f_part<<<dim3(B_ * 9, F_SPLIT), THREADS, 0, stream>>>(d2p, psi2, sfp);
    // 7) final reduce
    k_stage_f_red<<<(8 * SO3_DIM + THREADS - 1) / THREADS, THREADS, 0, stream>>>(sfp, out);
  } else {
    float* ws  = (float*)d_ws;
    float* y    = ws + WS_Y;
    float* psi  = ws + WS_PSI;
    float* z    = ws + WS_Z;
    float* s    = ws + WS_S;
    float* z2   = ws + WS_Z2;
    float* p2p  = ws + WS_P2P;
    float* psi2 = ws + WS_PSI2;

    k_stage_a3<<<NPAIR / 3, THREADS, 0, stream>>>(Fm, x, y);
    k_psi<<<(F_IN * F_SO3 * S2_DIM + THREADS - 1) / THREADS, THREADS, 0, stream>>>(w_s2, Y, psi);
    k_stage_c<<<B_ * F_SO3, THREADS, 0, stream>>>(y, psi, z);
    k_gemm_nt_relu<<<dim3(G_ACT / 64, (B_ * F_SO3 + 63) / 64), THREADS, 0, stream>>>(
        z, D_act, s, B_ * F_SO3, G_ACT, SO3_DIM);
    k_gemm_nn<<<dim3((SO3_DIM + 63) / 64, (B_ * F_SO3 + 63) / 64, 1), THREADS, 0, stream>>>(
        s, D_act, z2, B_ * F_SO3, SO3_DIM, G_ACT, G_ACT, 1.0f / G_ACT, 0);
    k_gemm_nn<<<dim3((SO3_DIM + 63) / 64, (F_SO3 + 63) / 64, 8), THREADS, 0, stream>>>(
        w_so3, D, p2p, F_SO3, SO3_DIM, G_SO3, G_SO3 / 8, 1.0f, (size_t)F_SO3 * SO3_DIM);
    k_reduce_psi2<<<(F_SO3 * SO3_DIM + THREADS - 1) / THREADS, THREADS, 0, stream>>>(p2p, psi2);
    k_stage_f<<<B_ * 9, THREADS, 0, stream>>>(z2, psi2, out, SO3_DIM);
  }
}